// Round 9
// baseline (232.413 us; speedup 1.0000x reference)
//
#include <hip/hip_runtime.h>

#define T_SEQ 2048
#define NHEAD 16
#define HD 64
#define CDIM 1024

typedef __bf16 bf16x8 __attribute__((ext_vector_type(8)));
typedef float f32x4 __attribute__((ext_vector_type(4)));
typedef float f32x16 __attribute__((ext_vector_type(16)));

union U16x8 { uint4 u4; unsigned short s[8]; bf16x8 b; };

__device__ __forceinline__ float bf2f(unsigned short u) {
    return __uint_as_float(((unsigned int)u) << 16);
}
__device__ __forceinline__ unsigned short f2bf(float f) {
    unsigned int u = __float_as_uint(f);
    u += 0x7fffu + ((u >> 16) & 1u);   // round-to-nearest-even
    return (unsigned short)(u >> 16);
}
__device__ __forceinline__ U16x8 load8f(const float* __restrict__ p) {
    U16x8 r;
    float4 f0 = *(const float4*)p;
    float4 f1 = *(const float4*)(p + 4);
    r.s[0] = f2bf(f0.x); r.s[1] = f2bf(f0.y); r.s[2] = f2bf(f0.z); r.s[3] = f2bf(f0.w);
    r.s[4] = f2bf(f1.x); r.s[5] = f2bf(f1.y); r.s[6] = f2bf(f1.z); r.s[7] = f2bf(f1.w);
    return r;
}

// async global->LDS, 16 B per lane; LDS dest = wave-uniform base + lane*16
__device__ __forceinline__ void async_copy16(const unsigned short* g, unsigned short* l) {
    __builtin_amdgcn_global_load_lds(
        (const __attribute__((address_space(1))) unsigned int*)g,
        (__attribute__((address_space(3))) unsigned int*)l, 16, 0, 0);
}

#define LOG2E 1.442695040f

// raw barrier / counted waits (NEVER __syncthreads in the 8-phase loop: it drains vmcnt)
#define BAR()    asm volatile("s_barrier" ::: "memory")
#define LGKM0()  asm volatile("s_waitcnt lgkmcnt(0)" ::: "memory")
#define VMC6()   asm volatile("s_waitcnt vmcnt(6)" ::: "memory")
#define VMC0()   asm volatile("s_waitcnt vmcnt(0)" ::: "memory")

// v_cvt_pk_bf16_f32: D.lo = bf16(lo), D.hi = bf16(hi)
__device__ __forceinline__ unsigned int cvtpk_bf16(float lo, float hi) {
    unsigned int r;
    asm("v_cvt_pk_bf16_f32 %0, %1, %2" : "=v"(r) : "v"(lo), "v"(hi));
    return r;
}
// x' = {x[0:31], y[0:31]}, y' = {x[32:63], y[32:63]}
__device__ __forceinline__ void plane32swap(unsigned int &x, unsigned int &y) {
    asm("v_permlane32_swap_b32 %0, %1" : "+v"(x), "+v"(y));
}

// ---------------------------------------------------------------------------
// Merged prep kernel (R7-verified): conv + both weight transposes.
// ---------------------------------------------------------------------------
__device__ __forceinline__ void transpose_tile(
    const float* __restrict__ in, unsigned short* __restrict__ out,
    int R, int C, int r0, int c0, float tile[64][65])
{
    const int tid = threadIdx.x;
    const int rr = tid >> 4;
    const int cc = (tid & 15) * 4;
#pragma unroll
    for (int p = 0; p < 4; ++p) {
        float4 v = *(const float4*)&in[(size_t)(r0 + p * 16 + rr) * C + c0 + cc];
        tile[p * 16 + rr][cc] = v.x;
        tile[p * 16 + rr][cc + 1] = v.y;
        tile[p * 16 + rr][cc + 2] = v.z;
        tile[p * 16 + rr][cc + 3] = v.w;
    }
    __syncthreads();
    const int n = tid >> 2;
    const int s = (tid & 3) * 8;
#pragma unroll
    for (int p = 0; p < 2; ++p) {
        const int k = s + p * 32;
        U16x8 o;
#pragma unroll
        for (int j = 0; j < 8; ++j) o.s[j] = f2bf(tile[k + j][n]);
        *(uint4*)&out[(size_t)(c0 + n) * R + r0 + k] = o.u4;
    }
}

__global__ __launch_bounds__(256) void prep(
    const float* __restrict__ X,     unsigned short* __restrict__ Xb,
    const float* __restrict__ Wqkv,  unsigned short* __restrict__ Wqkvt,
    const float* __restrict__ Wproj, unsigned short* __restrict__ Wprojt)
{
    __shared__ float tile[64][65];
    const int bid = blockIdx.x;
    if (bid < 2048) {
        const int i = (bid * 256 + threadIdx.x) * 8;
        U16x8 o = load8f(&X[i]);
        *(uint4*)&Xb[i] = o.u4;
    } else if (bid < 2816) {
        const int u = bid - 2048;
        transpose_tile(Wqkv, Wqkvt, CDIM, 3 * CDIM, (u & 15) * 64, (u >> 4) * 64, tile);
    } else {
        const int u = bid - 2816;
        transpose_tile(Wproj, Wprojt, CDIM, CDIM, (u & 15) * 64, (u >> 4) * 64, tile);
    }
}

// ---------------------------------------------------------------------------
// m97-style GEMM core (kept for proj): C[128x128] = A[M,K] * Bt[N,K]^T
// ---------------------------------------------------------------------------
__device__ __forceinline__ void gemm128_core(
    const unsigned short* __restrict__ A,
    const unsigned short* __restrict__ Bt,
    int K, int m0, int n0,
    unsigned short* As, unsigned short* Bs, f32x4 acc[4][4])
{
    const int tid = threadIdx.x;
    const int w = tid >> 6, lane = tid & 63;
    const int ln = lane & 15, quad = lane >> 4;
    const int wm = w >> 1, wn = w & 1;
    const int lr = lane >> 3;        // 0..7
    const int lc = (lane & 7) * 8;   // col start (elems)

    for (int kb = 0; kb < K; kb += 64) {
        __syncthreads();
#pragma unroll
        for (int i = 0; i < 4; ++i) {
            async_copy16(&A[(size_t)(m0 + w * 32 + i * 8 + lr) * K + kb + lc],
                         &As[(w * 32 + i * 8) * 64]);
            async_copy16(&Bt[(size_t)(n0 + w * 32 + i * 8 + lr) * K + kb + lc],
                         &Bs[(w * 32 + i * 8) * 64]);
        }
        __syncthreads();
#pragma unroll
        for (int kk = 0; kk < 2; ++kk) {
            U16x8 af[4], bff[4];
#pragma unroll
            for (int i = 0; i < 4; ++i)
                af[i].u4 = *(const uint4*)&As[(wm * 64 + i * 16 + ln) * 64 + kk * 32 + quad * 8];
#pragma unroll
            for (int j = 0; j < 4; ++j)
                bff[j].u4 = *(const uint4*)&Bs[(wn * 64 + j * 16 + ln) * 64 + kk * 32 + quad * 8];
#pragma unroll
            for (int i = 0; i < 4; ++i)
#pragma unroll
                for (int j = 0; j < 4; ++j)
                    acc[i][j] = __builtin_amdgcn_mfma_f32_16x16x32_bf16(af[i].b, bff[j].b, acc[i][j], 0, 0, 0);
        }
    }
}

// ---------------------------------------------------------------------------
// 256x256 8-phase counted-vmcnt GEMM (T2+T3+T4+T5), fused QKV epilogue.
// R9 change: Q slice pre-scaled by 0.125 (folds 1/sqrt(hd) out of flash).
// ---------------------------------------------------------------------------
__device__ __forceinline__ void stageA(const unsigned short* __restrict__ A,
                                       unsigned short* buf,
                                       int m0, int t, int unit, int w, int lane)
{
#pragma unroll
    for (int s = 0; s < 2; ++s) {
        const int r0 = s * 128 + unit * 64 + w * 8;          // wave-uniform
        const int row = r0 + (lane >> 3);
        const int col = (16 * (lane & 7)) ^ ((row & 4) ? 32 : 0);  // bytes, pre-swizzled src
        const unsigned short* src = A + (size_t)(m0 + row) * CDIM + t * 64 + (col >> 1);
        async_copy16(src, buf + r0 * 64);                    // linear LDS dest
    }
}

__device__ __forceinline__ void stageB(const unsigned short* __restrict__ B,
                                       unsigned short* buf,
                                       int n0, int t, int unit, int w, int lane)
{
#pragma unroll
    for (int s = 0; s < 2; ++s) {
        const int slice = s * 8 + w;
        const int r0 = (slice >> 2) * 64 + unit * 32 + (slice & 3) * 8;  // wave-uniform
        const int row = r0 + (lane >> 3);
        const int col = (16 * (lane & 7)) ^ ((row & 4) ? 32 : 0);
        const unsigned short* src = B + (size_t)(n0 + row) * CDIM + t * 64 + (col >> 1);
        async_copy16(src, buf + r0 * 64);
    }
}

__device__ __forceinline__ void readA(U16x8 af[4][2], const unsigned short* buf,
                                      int wm, int qm, int ln, int quad)
{
#pragma unroll
    for (int i = 0; i < 4; ++i) {
        const int row = wm * 128 + qm * 64 + i * 16 + ln;
        const int sw = (row & 4) ? 32 : 0;
#pragma unroll
        for (int kk = 0; kk < 2; ++kk) {
            const int byt = row * 128 + ((kk * 64 + quad * 16) ^ sw);
            af[i][kk].u4 = *(const uint4*)((const char*)buf + byt);
        }
    }
}

__device__ __forceinline__ void readB(U16x8 bf[2][2], const unsigned short* buf,
                                      int wn, int qn, int ln, int quad)
{
#pragma unroll
    for (int jj = 0; jj < 2; ++jj) {
        const int row = wn * 64 + qn * 32 + jj * 16 + ln;
        const int sw = (row & 4) ? 32 : 0;
#pragma unroll
        for (int kk = 0; kk < 2; ++kk) {
            const int byt = row * 128 + ((kk * 64 + quad * 16) ^ sw);
            bf[jj][kk].u4 = *(const uint4*)((const char*)buf + byt);
        }
    }
}

template<int QM, int QN>
__device__ __forceinline__ void mfma16(f32x4 acc[8][4], const U16x8 af[4][2],
                                       const U16x8 bf[2][2])
{
    __builtin_amdgcn_s_setprio(1);
#pragma unroll
    for (int i = 0; i < 4; ++i)
#pragma unroll
        for (int jj = 0; jj < 2; ++jj)
#pragma unroll
            for (int kk = 0; kk < 2; ++kk)
                acc[QM * 4 + i][QN * 2 + jj] = __builtin_amdgcn_mfma_f32_16x16x32_bf16(
                    af[i][kk].b, bf[jj][kk].b, acc[QM * 4 + i][QN * 2 + jj], 0, 0, 0);
    __builtin_amdgcn_s_setprio(0);
}

__global__ __launch_bounds__(512) void qkv8(
    const unsigned short* __restrict__ Xb,    // [4096,1024] bf16
    const unsigned short* __restrict__ Wt,    // [3072,1024] bf16 (W^T; V rows at 2048)
    const float* __restrict__ bias,           // [3072]
    unsigned short* __restrict__ Qp,
    unsigned short* __restrict__ Kp,
    unsigned short* __restrict__ Vtp)         // [B,1024,T]
{
    __shared__ __align__(1024) unsigned short smem[4][16384];  // Abuf0,Abuf1,Bbuf0,Bbuf1
    unsigned short* Ab0 = smem[0];
    unsigned short* Ab1 = smem[1];
    unsigned short* Bb0 = smem[2];
    unsigned short* Bb1 = smem[3];

    const int tid = threadIdx.x;
    const int w = tid >> 6, lane = tid & 63;
    const int ln = lane & 15, quad = lane >> 4;
    const int wm = w >> 2, wn = w & 3;

    // bijective XCD swizzle (192 % 8 == 0): 24 consecutive tiles per XCD
    const int bid = blockIdx.x;
    const int swz = (bid & 7) * 24 + (bid >> 3);
    const int nt = swz % 12, mt = swz / 12;
    const int m0 = mt * 256, n0 = nt * 256;

    f32x4 acc[8][4];
#pragma unroll
    for (int i = 0; i < 8; ++i)
#pragma unroll
        for (int j = 0; j < 4; ++j) acc[i][j] = (f32x4){0.f, 0.f, 0.f, 0.f};

    // ---- prologue: 7 units (tile 0 complete + tile 1 A0/B0/B1), depth-3 pipe
    stageA(Xb, Ab0, m0, 0, 0, w, lane);
    stageB(Wt, Bb0, n0, 0, 0, w, lane);
    stageB(Wt, Bb0, n0, 0, 1, w, lane);
    stageA(Xb, Ab0, m0, 0, 1, w, lane);
    stageA(Xb, Ab1, m0, 1, 0, w, lane);
    stageB(Wt, Bb1, n0, 1, 0, w, lane);
    stageB(Wt, Bb1, n0, 1, 1, w, lane);
    VMC6();            // oldest 4 units (= tile 0) landed
    BAR();

    U16x8 af[4][2], bq0[2][2], bq1[2][2];

    // ---- main loop: 7 iters x 2 K-tiles; tiles 0..13
    for (int j = 0; j < 7; ++j) {
        const int e = 2 * j, o = 2 * j + 1;
        // P1: quad(0,0) of tile e  | stage A1(o) -> buf1
        readA(af, Ab0, wm, 0, ln, quad);
        readB(bq0, Bb0, wn, 0, ln, quad);
        stageA(Xb, Ab1, m0, o, 1, w, lane);
        BAR(); LGKM0();
        mfma16<0, 0>(acc, af, bq0);
        LGKM0(); BAR();
        // P2: quad(0,1)            | stage A0(e+2) -> buf0
        readB(bq1, Bb0, wn, 1, ln, quad);
        stageA(Xb, Ab0, m0, e + 2, 0, w, lane);
        BAR(); LGKM0();
        mfma16<0, 1>(acc, af, bq1);
        LGKM0(); BAR();
        // P3: quad(1,0)            | stage B0(e+2)
        readA(af, Ab0, wm, 1, ln, quad);
        stageB(Wt, Bb0, n0, e + 2, 0, w, lane);
        BAR(); LGKM0();
        mfma16<1, 0>(acc, af, bq0);
        LGKM0(); BAR();
        // P4: quad(1,1)            | stage B1(e+2) ; counted wait
        stageB(Wt, Bb0, n0, e + 2, 1, w, lane);
        BAR();
        mfma16<1, 1>(acc, af, bq1);
        VMC6(); BAR();
        // P5: quad(0,0) of tile o  | stage A1(e+2) -> buf0
        readA(af, Ab1, wm, 0, ln, quad);
        readB(bq0, Bb1, wn, 0, ln, quad);
        stageA(Xb, Ab0, m0, e + 2, 1, w, lane);
        BAR(); LGKM0();
        mfma16<0, 0>(acc, af, bq0);
        LGKM0(); BAR();
        // P6: quad(0,1)            | stage A0(o+2) -> buf1
        readB(bq1, Bb1, wn, 1, ln, quad);
        stageA(Xb, Ab1, m0, o + 2, 0, w, lane);
        BAR(); LGKM0();
        mfma16<0, 1>(acc, af, bq1);
        LGKM0(); BAR();
        // P7: quad(1,0)            | stage B0(o+2)
        readA(af, Ab1, wm, 1, ln, quad);
        stageB(Wt, Bb1, n0, o + 2, 0, w, lane);
        BAR(); LGKM0();
        mfma16<1, 0>(acc, af, bq0);
        LGKM0(); BAR();
        // P8: quad(1,1)            | stage B1(o+2) ; counted wait
        stageB(Wt, Bb1, n0, o + 2, 1, w, lane);
        BAR();
        mfma16<1, 1>(acc, af, bq1);
        VMC6(); BAR();
    }

    // ---- epilogue: tiles 14 (buf0), 15 (buf1); stage last unit then drain
    stageA(Xb, Ab1, m0, 15, 1, w, lane);
    VMC0(); BAR();

    readA(af, Ab0, wm, 0, ln, quad);
    readB(bq0, Bb0, wn, 0, ln, quad);
    readB(bq1, Bb0, wn, 1, ln, quad);
    mfma16<0, 0>(acc, af, bq0);
    mfma16<0, 1>(acc, af, bq1);
    readA(af, Ab0, wm, 1, ln, quad);
    mfma16<1, 0>(acc, af, bq0);
    mfma16<1, 1>(acc, af, bq1);

    readA(af, Ab1, wm, 0, ln, quad);
    readB(bq0, Bb1, wn, 0, ln, quad);
    readB(bq1, Bb1, wn, 1, ln, quad);
    mfma16<0, 0>(acc, af, bq0);
    mfma16<0, 1>(acc, af, bq1);
    readA(af, Ab1, wm, 1, ln, quad);
    mfma16<1, 0>(acc, af, bq0);
    mfma16<1, 1>(acc, af, bq1);

    // ---- C epilogue: n-tile selects Q / K / V^T (BN=256 divides 1024)
    const int which = n0 >> 10;
    float bv[4];
#pragma unroll
    for (int jj = 0; jj < 4; ++jj) bv[jj] = bias[n0 + wn * 64 + jj * 16 + ln];

    if (which < 2) {
        unsigned short* dst = (which == 0) ? Qp : Kp;
        const float qsc = (which == 0) ? 0.125f : 1.0f;   // fold 1/sqrt(hd) into Q
#pragma unroll
        for (int jj = 0; jj < 4; ++jj) {
            const int n = n0 + wn * 64 + jj * 16 + ln;
            const int h = (n >> 6) & 15, d = n & 63;
#pragma unroll
            for (int i = 0; i < 8; ++i)
#pragma unroll
                for (int r = 0; r < 4; ++r) {
                    const int m = m0 + wm * 128 + i * 16 + quad * 4 + r;
                    const int b = m >> 11, tt = m & 2047;
                    dst[(((size_t)(b * NHEAD + h) * T_SEQ) + tt) * HD + d] =
                        f2bf((acc[i][jj][r] + bv[jj]) * qsc);
                }
        }
    } else {
#pragma unroll
        for (int jj = 0; jj < 4; ++jj) {
            const int n = n0 + wn * 64 + jj * 16 + ln;
            const int c = n - 2048;                       // channel h*64+d
#pragma unroll
            for (int i = 0; i < 8; ++i) {
                const int m00 = m0 + wm * 128 + i * 16 + quad * 4;  // 4 consecutive tokens
                const int b = m00 >> 11, tt = m00 & 2047;
                ushort4 pk;
                pk.x = f2bf(acc[i][jj][0] + bv[jj]);
                pk.y = f2bf(acc[i][jj][1] + bv[jj]);
                pk.z = f2bf(acc[i][jj][2] + bv[jj]);
                pk.w = f2bf(acc[i][jj][3] + bv[jj]);
                *(ushort4*)&Vtp[(size_t)(b * 1024 + c) * T_SEQ + tt] = pk;
            }
        }
    }
}

// ---------------------------------------------------------------------------
// Kernel: proj GEMM -> fp32 out.  n-tiles on blockIdx.x (XCD L2).
// ---------------------------------------------------------------------------
__global__ __launch_bounds__(256) void proj_gemm(
    const unsigned short* __restrict__ Yin,   // [4096,1024] bf16
    const unsigned short* __restrict__ Wt,    // [1024,1024] bf16 (W^T)
    const float* __restrict__ bias,           // [1024]
    float* __restrict__ out)                  // [4096,1024] fp32
{
    __shared__ unsigned short As[128 * 64];
    __shared__ unsigned short Bs[128 * 64];
    const int m0 = blockIdx.y * 128;
    const int n0 = blockIdx.x * 128;

    f32x4 acc[4][4];
#pragma unroll
    for (int i = 0; i < 4; ++i)
#pragma unroll
        for (int j = 0; j < 4; ++j) acc[i][j] = (f32x4){0.f, 0.f, 0.f, 0.f};

    gemm128_core(Yin, Wt, CDIM, m0, n0, As, Bs, acc);

    const int tid = threadIdx.x;
    const int w = tid >> 6, lane = tid & 63;
    const int ln = lane & 15, quad = lane >> 4;
    const int wm = w >> 1, wn = w & 1;

#pragma unroll
    for (int j = 0; j < 4; ++j) {
        const int n = n0 + wn * 64 + j * 16 + ln;
        const float bv = bias[n];
#pragma unroll
        for (int i = 0; i < 4; ++i)
#pragma unroll
            for (int r = 0; r < 4; ++r) {
                const int m = m0 + wm * 64 + i * 16 + quad * 4 + r;
                out[(size_t)m * CDIM + n] = acc[i][j][r] + bv;
            }
    }
}

// ---------------------------------------------------------------------------
// Flash attention, double-width k-steps (128 tokens per barrier round).
//   Per step: stage Ks[128][64] + Vs[2][64][64] (32 KB), then process the
//   two 64-wide halves back-to-back from LDS (body math identical to the
//   R2/R8-verified kernel; Q is pre-scaled by 0.125 in qkv8).
//   grid (32 bh, 24): y<16 split qb=15-(y>>1) by even/odd DOUBLE-tile
//   (sgk=y&1); y>=16 unsplit qb=23-y.  All chains <= 8-9 double-steps.
//   merge_attn combines split pairs (unchanged).
// ---------------------------------------------------------------------------

// ushort index in a [R][64] bf16 tile; slot = 16B-chunk 0..7, XOR-swizzled
__device__ __forceinline__ int swz(int row, int slot) {
    return row * 64 + ((slot ^ (row & 7)) << 3);
}

__global__ __launch_bounds__(256, 2) void flash_attn32(
    const unsigned short* __restrict__ Qp,   // [BH, T, 64]  (Q pre-scaled 0.125)
    const unsigned short* __restrict__ Kp,   // [BH, T, 64]
    const unsigned short* __restrict__ Vtp,  // [BH, 64, T]
    const int* __restrict__ mask,            // [B, T]
    unsigned short* __restrict__ Y,          // [B*T, 1024] bf16
    unsigned short* __restrict__ Po,         // [32*8*2, 128, 64] bf16 partial O
    float* __restrict__ Pm,                  // [32*8*2, 128] partial m
    float* __restrict__ Pl)                  // [32*8*2, 128] partial l
{
    __shared__ unsigned short Ks[128 * 64];  // 128 tokens x 64 d (swizzled)
    __shared__ unsigned short Vs[2][64 * 64];// per-half V^T: 64 d x 64 tokens
    __shared__ float mask_arr[128];          // permuted to reg order, 2 halves
    __shared__ float als[4][32];             // per-warp alpha / 1/l broadcast
    __shared__ int flagu[2];                 // per half: 0 = all 64 tokens valid

    const int bh = blockIdx.x;
    const int y = blockIdx.y;
    int qb, j0, jstep;
    bool split;
    if (y < 16) { qb = 15 - (y >> 1); j0 = y & 1; jstep = 2; split = true; }
    else        { qb = 23 - y;        j0 = 0;     jstep = 1; split = false; }
    const int sgk = y & 1;                   // segment id (split only)

    const int b = bh >> 4, h = bh & 15;
    const int tid = threadIdx.x;
    const int w = tid >> 6, lane = tid & 63;
    const int l31 = lane & 31, hi = lane >> 5;
    const int row8 = tid >> 3, seg = tid & 7;
    const size_t base = (size_t)bh * T_SEQ * HD;
    const int qB = qb * 128;
    const int qw0 = qB + w * 32;
    const int qv = qw0 + l31;                // this lane's softmax q-row
    const int j2last = qb;                   // double-tiles 0..qb

    // Q fragments: qf[c] = Q[qv][c*16 + hi*8 .. +8]  (B-operand of swapped QK^T)
    U16x8 qf[4];
    {
        const unsigned short* qrow = &Qp[base + (size_t)qv * HD];
#pragma unroll
        for (int c = 0; c < 4; ++c)
            qf[c].u4 = *(const uint4*)&qrow[c * 16 + hi * 8];
    }

    f32x16 oA0, oA1;
#pragma unroll
    for (int r = 0; r < 16; ++r) { oA0[r] = 0.f; oA1[r] = 0.f; }
    float m_r = -3.0e38f, mL = 0.f, l_r = 0.f;

    // register prefetch of double-tile j0: K rows row8+32i, V halves x rows
    uint4 kr[4], vr[4];
    float mf = 0.f;
    {
        const unsigned short* kp0 = &Kp[base + (size_t)(j0 * 128 + row8) * HD + seg * 8];
#pragma unroll
        for (int i = 0; i < 4; ++i)
            kr[i] = *(const uint4*)(kp0 + (size_t)(32 * i) * HD);
#pragma unroll
        for (int hh = 0; hh < 2; ++hh) {
            const unsigned short* vp0 = &Vtp[base + (size_t)row8 * T_SEQ + j0 * 128 + hh * 64 + seg * 8];
            vr[hh * 2]     = *(const uint4*)vp0;
            vr[hh * 2 + 1] = *(const uint4*)(vp0 + 32 * T_SEQ);
        }
        if (tid < 128) mf = mask[b * T_SEQ + j0 * 128 + tid] ? 0.f : -1.0e30f;
    }

    for (int j2 = j0; j2 <= j2last; j2 += jstep) {
        __syncthreads();
#pragma unroll
        for (int i = 0; i < 4; ++i)
            *(uint4*)&Ks[swz(row8 + 32 * i, seg)] = kr[i];
#pragma unroll
        for (int hh = 0; hh < 2; ++hh) {
            *(uint4*)&Vs[hh][swz(row8, seg)]      = vr[hh * 2];
            *(uint4*)&Vs[hh][swz(row8 + 32, seg)] = vr[hh * 2 + 1];
        }
        if (w < 2) {
            // mask value for token k = w*64+lane -> reg-order slot within half
            const int kk = lane;
            const int idx = w * 64 + ((kk >> 2) & 1) * 32 + (kk >> 5) * 16
                          + ((kk & 31) >> 3) * 4 + (kk & 3);
            mask_arr[idx] = mf;
            const unsigned long long bb = __ballot(mf == 0.f);
            if (lane == 0) flagu[w] = (bb == 0xFFFFFFFFFFFFFFFFull) ? 0 : 1;
        }
        __syncthreads();

        const int jn = j2 + jstep;
        if (jn <= j2last) {   // prefetch next double-tile of this segment
            const unsigned short* kp0 = &Kp[base + (size_t)(jn * 128 + row8) * HD + seg * 8];
#pragma unroll
            for (int i = 0; i < 4; ++i)
                kr[i] = *(const uint4*)(kp0 + (size_t)(32 * i) * HD);
#pragma unroll
            for (int hh = 0; hh < 2; ++hh) {
                const unsigned short* vp0 = &Vtp[base + (size_t)row8 * T_SEQ + jn * 128 + hh * 64 + seg * 8];
                vr[hh * 2]     = *(const uint4*)vp0;
                vr[hh * 2 + 1] = *(const uint4*)(vp0 + 32 * T_SEQ);
            }
            if (tid < 128) mf = mask[b * T_SEQ + jn * 128 + tid] ? 0.f : -1.0e30f;
        }

        // ---- two 64-wide halves from LDS, back-to-back (no barrier between)
#pragma unroll
        for (int hh = 0; hh < 2; ++hh) {
            const int kst = j2 * 128 + hh * 64;
            if (kst > qw0 + 31) continue;
            const bool edge = (kst + 63 > qw0);
            const int anymask = flagu[hh];

            // ---- S^T = K Q^T  (two 32-k sub-halves; Q pre-scaled)
            f32x16 sc0, sc1;
#pragma unroll
            for (int r = 0; r < 16; ++r) { sc0[r] = 0.f; sc1[r] = 0.f; }
#pragma unroll
            for (int c = 0; c < 4; ++c) {
                U16x8 ka0, ka1;
                const int r0 = hh * 64 + l31, r1 = hh * 64 + 32 + l31;
                ka0.u4 = *(const uint4*)&Ks[r0 * 64 + (((2 * c + hi) ^ (r0 & 7)) << 3)];
                ka1.u4 = *(const uint4*)&Ks[r1 * 64 + (((2 * c + hi) ^ (r1 & 7)) << 3)];
                sc0 = __builtin_amdgcn_mfma_f32_32x32x16_bf16(ka0.b, qf[c].b, sc0, 0, 0, 0);
                sc1 = __builtin_amdgcn_mfma_f32_32x32x16_bf16(ka1.b, qf[c].b, sc1, 0, 0, 0);
            }

            // ---- pad mask (pure add; scale already folded into Q)
            if (anymask) {
#pragma unroll
                for (int g = 0; g < 4; ++g) {
                    const f32x4 m0v = *(const f32x4*)&mask_arr[hh * 64 + hi * 32 + g * 4];
                    const f32x4 m1v = *(const f32x4*)&mask_arr[hh * 64 + hi * 32 + 16 + g * 4];
#pragma unroll
                    for (int t = 0; t < 4; ++t) {
                        sc0[g * 4 + t] += m0v[t];
                        sc1[g * 4 + t] += m1v[t];
                    }
                }
            }
            // ---- causal edge: k_global > q -> -inf
            if (edge) {
#pragma unroll
                for (int r = 0; r < 16; ++r) {
                    const int krow = (r & 3) + 8 * (r >> 2) + 4 * hi;
                    if (kst + krow > qv)      sc0[r] = -1.0e30f;
                    if (kst + 32 + krow > qv) sc1[r] = -1.0e30f;
                }
            }

            // ---- tile max (in-lane 32 values, then lane<->lane+32 merge)
            float tm = -3.0e38f;
#pragma unroll
            for (int r = 0; r < 16; ++r)
                tm = fmaxf(tm, fmaxf(sc0[r], sc1[r]));
            tm = fmaxf(tm, __shfl_xor(tm, 32));

            // ---- defer-max: rescale only if max grew > THR
            if (__any(tm > m_r + 8.f)) {
                const float mn = fmaxf(m_r, tm);
                const float a = __builtin_amdgcn_exp2f((m_r - mn) * LOG2E);
                m_r = mn; mL = mn * LOG2E;
                l_r *= a;
                if (hi == 0) als[w][l31] = a;      // alpha indexed by q
                f32x4 av[4];
#pragma unroll
                for (int g = 0; g < 4; ++g)
                    av[g] = *(const f32x4*)&als[w][g * 8 + hi * 4];
#pragma unroll
                for (int r = 0; r < 16; ++r) {
                    const float aa = av[r >> 2][r & 3];
                    oA0[r] *= aa; oA1[r] *= aa;
                }
            }

            // ---- exp + per-lane partial sum
            float ps = 0.f;
#pragma unroll
            for (int r = 0; r < 16; ++r) {
                const float p0 = __builtin_amdgcn_exp2f(fmaf(sc0[r], LOG2E, -mL));
                const float p1 = __builtin_amdgcn_exp2f(fmaf(sc1[r], LOG2E, -mL));
                sc0[r] = p0; sc1[r] = p1;
                ps += p0 + p1;
            }
            l_r += ps;

            // ---- P -> bf16 A-frags (cvt_pk + permlane32_swap) ; O += P V
#pragma unroll
            for (int c = 0; c < 4; ++c) {
                const int rb = (c & 1) * 8;
                unsigned int x0, y0, x1, y1;
                if (c < 2) {
                    x0 = cvtpk_bf16(sc0[rb + 0], sc0[rb + 1]);
                    y0 = cvtpk_bf16(sc0[rb + 4], sc0[rb + 5]);
                    x1 = cvtpk_bf16(sc0[rb + 2], sc0[rb + 3]);
                    y1 = cvtpk_bf16(sc0[rb + 6], sc0[rb + 7]);
                } else {
                    x0 = cvtpk_bf16(sc1[rb + 0], sc1[rb + 1]);
                    y0 = cvtpk_bf16(sc1[rb + 4], sc1[rb + 5]);
                    x1 = cvtpk_bf16(sc1[rb + 2], sc1[rb + 3]);
                    y1 = cvtpk_bf16(sc1[rb + 6], sc1[rb + 7]);
                }
                plane32swap(x0, y0);   // x0 -> au[0] (j=0,1), y0 -> au[2] (j=4,5)
                plane32swap(x1, y1);   // x1 -> au[1] (j=2,3), y1 -> au[3] (j=6,7)
                U16x8 pa;
                pa.u4 = make_uint4(x0, x1, y0, y1);
                {
                    const int vr_0 = l31, vr_1 = 32 + l31;
                    U16x8 vb0, vb1;
                    vb0.u4 = *(const uint4*)&Vs[hh][vr_0 * 64 + (((2 * c + hi) ^ (vr_0 & 7)) << 3)];
                    vb1.u4 = *(const uint4*)&Vs[hh][vr_1 * 64 + (((2 * c + hi) ^ (vr_1 & 7)) << 3)];
                    oA0 = __builtin_amdgcn_mfma_f32_32x32x16_bf16(pa.b, vb0.b, oA0, 0, 0, 0);
                    oA1 = __builtin_amdgcn_mfma_f32_32x32x16_bf16(pa.b, vb1.b, oA1, 0, 0, 0);
                }
            }
        }
    }

    // ---- hi-merge of the row-sum partial (each lane covers its hi-half)
    const float lt = l_r + __shfl_xor(l_r, 32);

    if (split) {
        // ---- write unnormalized partials (O-layout rows, lane-q m/l)
        const int pidx = (bh * 8 + (qb - 8)) * 2 + sgk;
        if (hi == 0) {
            Pm[pidx * 128 + w * 32 + l31] = m_r;
            Pl[pidx * 128 + w * 32 + l31] = lt;
        }
#pragma unroll
        for (int r = 0; r < 16; ++r) {
            const int qlc = w * 32 + (r & 3) + 8 * (r >> 2) + 4 * hi;
            Po[(size_t)pidx * 8192 + qlc * 64 + l31]      = f2bf(oA0[r]);
            Po[(size_t)pidx * 8192 + qlc * 64 + 32 + l31] = f2bf(oA1[r]);
        }
    } else {
        // ---- normalize + store
        if (hi == 0) als[w][l31] = 1.0f / lt;
        f32x4 lv[4];
#pragma unroll
        for (int g = 0; g < 4; ++g)
            lv[g] = *(const f32x4*)&als[w][g * 8 + hi * 4];
#pragma unroll
        for (int r = 0; r < 16; ++r) {
            const int q = qw0 + (r & 3) + 8 * (r >> 2) + 4 * hi;
            const float sl = lv[r >> 2][r & 3];
            const size_t row = (size_t)(b * T_SEQ + q);
            Y[row * CDIM + h * HD + l31]      = f2bf(oA0[r] * sl);
            Y[row * CDIM + h * HD + 32 + l31] = f2bf(oA1[r] * sl);
        }
    }
}

// ---------------------------------------------------------------------------
// Merge the two k-segments of each split (bh, qb>=8) chunk.
//   O = (f0*O0 + f1*O1) / (f0*l0 + f1*l1),  f_i = exp(m_i - max(m0,m1)).
//   grid 1024 = 32 bh x 8 qc x 4 parts; thread -> (q row, 8 d cols).
// ---------------------------------------------------------------------------
__global__ __launch_bounds__(256) void merge_attn(
    const unsigned short* __restrict__ Po,
    const float* __restrict__ Pm, const float* __restrict__ Pl,
    unsigned short* __restrict__ Y)
{
    const int u = blockIdx.x;
    const int bh = u & 31;
    const int v = u >> 5;                 // 0..31
    const int qc = v >> 2, part = v & 3;
    const int tid = threadIdx.x;
    const int ql = part * 32 + (tid >> 3);
    const int d0 = (tid & 7) * 8;
    const int b = bh >> 4, h = bh & 15;
    const int i0 = (bh * 8 + qc) * 2, i1 = i0 + 1;

    const float m0 = Pm[i0 * 128 + ql], m1 = Pm[i1 * 128 + ql];
    const float l0 = Pl[i0 * 128 + ql], l1 = Pl[i1 * 128 + ql];
    const float M = fmaxf(m0, m1);
    const float f0 = __builtin_amdgcn_exp2f((m0 - M) * LOG2E);
    const float f1 = __builtin_amdgcn_exp2f((m1 - M) * LOG2E);
    const float inv = 1.0f / (f0 * l0 + f1 * l1);

    U16x8 a, c, o;
    a.u4 = *(const uint4*)&Po[(size_t)i0 * 8192 + ql * 64 + d0];
    c.u4 = *(const uint4*)&Po[(size_t)i1 * 8192 + ql * 64 + d0];
#pragma unroll
    for (int j = 0; j < 8; ++j)
        o.s[j] = f2bf((f0 * bf2f(a.s[j]) + f1 * bf2f(c.s[j])) * inv);

    const int q = 1024 + qc * 128 + ql;
    *(uint4*)&Y[(size_t)(b * T_SEQ + q) * CDIM + h * HD + d0] = o.u4;
}

// ---------------------------------------------------------------------------
extern "C" void kernel_launch(void* const* d_in, const int* in_sizes, int n_in,
                              void* d_out, int out_size, void* d_ws, size_t ws_size,
                              hipStream_t stream)
{
    const float* X     = (const float*)d_in[0];
    const int*   mask  = (const int*)d_in[1];
    const float* Wqkv  = (const float*)d_in[2];
    const float* bqkv  = (const float*)d_in[3];
    const float* Wproj = (const float*)d_in[4];
    const float* bproj = (const float*)d_in[5];
    float* out = (float*)d_out;

    const size_t per = (size_t)2 * NHEAD * T_SEQ * HD;   // 4,194,304 elems
    unsigned short* Qp     = (unsigned short*)d_ws;
    unsigned short* Kp     = Qp + per;
    unsigned short* Vtp    = Kp + per;
    unsigned short* Xb     = Vtp + per;                  // aliased: Yp reuses Xb
    unsigned short* Yp     = Xb;                         // X consumed before Y written
    unsigned short* Wqkvt  = Xb + per;                   // [3072,1024]
    unsigned short* Wprojt = Wqkvt + (size_t)3 * CDIM * CDIM;  // [1024,1024]
    unsigned short* Po     = Wprojt + (size_t)CDIM * CDIM;     // [512,128,64] bf16
    float*          Pm     = (float*)(Po + (size_t)512 * 8192);
    float*          Pl     = Pm + 512 * 128;

    prep<<<3072, 256, 0, stream>>>(X, Xb, Wqkv, Wqkvt, Wproj, Wprojt);
    qkv8<<<192, 512, 0, stream>>>(Xb, Wqkvt, bqkv, Qp, Kp, Vtp);
    flash_attn32<<<dim3(2 * NHEAD, 24), 256, 0, stream>>>(Qp, Kp, Vtp, mask, Yp, Po, Pm, Pl);
    merge_attn<<<1024, 256, 0, stream>>>(Po, Pm, Pl, Yp);
    proj_gemm<<<dim3(8, 32), 256, 0, stream>>>(Yp, Wprojt, bproj, out);
}

// Round 10
// 214.715 us; speedup vs baseline: 1.0824x; 1.0824x over previous
//
#include <hip/hip_runtime.h>

#define T_SEQ 2048
#define NHEAD 16
#define HD 64
#define CDIM 1024

typedef __bf16 bf16x8 __attribute__((ext_vector_type(8)));
typedef float f32x4 __attribute__((ext_vector_type(4)));
typedef float f32x16 __attribute__((ext_vector_type(16)));

union U16x8 { uint4 u4; unsigned short s[8]; bf16x8 b; };

__device__ __forceinline__ float bf2f(unsigned short u) {
    return __uint_as_float(((unsigned int)u) << 16);
}
__device__ __forceinline__ unsigned short f2bf(float f) {
    unsigned int u = __float_as_uint(f);
    u += 0x7fffu + ((u >> 16) & 1u);   // round-to-nearest-even
    return (unsigned short)(u >> 16);
}
__device__ __forceinline__ U16x8 load8f(const float* __restrict__ p) {
    U16x8 r;
    float4 f0 = *(const float4*)p;
    float4 f1 = *(const float4*)(p + 4);
    r.s[0] = f2bf(f0.x); r.s[1] = f2bf(f0.y); r.s[2] = f2bf(f0.z); r.s[3] = f2bf(f0.w);
    r.s[4] = f2bf(f1.x); r.s[5] = f2bf(f1.y); r.s[6] = f2bf(f1.z); r.s[7] = f2bf(f1.w);
    return r;
}

// async global->LDS, 16 B per lane; LDS dest = wave-uniform base + lane*16
__device__ __forceinline__ void async_copy16(const unsigned short* g, unsigned short* l) {
    __builtin_amdgcn_global_load_lds(
        (const __attribute__((address_space(1))) unsigned int*)g,
        (__attribute__((address_space(3))) unsigned int*)l, 16, 0, 0);
}

#define LOG2E 1.442695040f

// raw barrier / counted waits (NEVER __syncthreads in the 8-phase loop: it drains vmcnt)
#define BAR()    asm volatile("s_barrier" ::: "memory")
#define LGKM0()  asm volatile("s_waitcnt lgkmcnt(0)" ::: "memory")
#define VMC6()   asm volatile("s_waitcnt vmcnt(6)" ::: "memory")
#define VMC0()   asm volatile("s_waitcnt vmcnt(0)" ::: "memory")

// v_cvt_pk_bf16_f32: D.lo = bf16(lo), D.hi = bf16(hi)
__device__ __forceinline__ unsigned int cvtpk_bf16(float lo, float hi) {
    unsigned int r;
    asm("v_cvt_pk_bf16_f32 %0, %1, %2" : "=v"(r) : "v"(lo), "v"(hi));
    return r;
}
// x' = {x[0:31], y[0:31]}, y' = {x[32:63], y[32:63]}
__device__ __forceinline__ void plane32swap(unsigned int &x, unsigned int &y) {
    asm("v_permlane32_swap_b32 %0, %1" : "+v"(x), "+v"(y));
}

// ---------------------------------------------------------------------------
// Merged prep kernel (R7-verified): conv + both weight transposes.
// ---------------------------------------------------------------------------
__device__ __forceinline__ void transpose_tile(
    const float* __restrict__ in, unsigned short* __restrict__ out,
    int R, int C, int r0, int c0, float tile[64][65])
{
    const int tid = threadIdx.x;
    const int rr = tid >> 4;
    const int cc = (tid & 15) * 4;
#pragma unroll
    for (int p = 0; p < 4; ++p) {
        float4 v = *(const float4*)&in[(size_t)(r0 + p * 16 + rr) * C + c0 + cc];
        tile[p * 16 + rr][cc] = v.x;
        tile[p * 16 + rr][cc + 1] = v.y;
        tile[p * 16 + rr][cc + 2] = v.z;
        tile[p * 16 + rr][cc + 3] = v.w;
    }
    __syncthreads();
    const int n = tid >> 2;
    const int s = (tid & 3) * 8;
#pragma unroll
    for (int p = 0; p < 2; ++p) {
        const int k = s + p * 32;
        U16x8 o;
#pragma unroll
        for (int j = 0; j < 8; ++j) o.s[j] = f2bf(tile[k + j][n]);
        *(uint4*)&out[(size_t)(c0 + n) * R + r0 + k] = o.u4;
    }
}

__global__ __launch_bounds__(256) void prep(
    const float* __restrict__ X,     unsigned short* __restrict__ Xb,
    const float* __restrict__ Wqkv,  unsigned short* __restrict__ Wqkvt,
    const float* __restrict__ Wproj, unsigned short* __restrict__ Wprojt)
{
    __shared__ float tile[64][65];
    const int bid = blockIdx.x;
    if (bid < 2048) {
        const int i = (bid * 256 + threadIdx.x) * 8;
        U16x8 o = load8f(&X[i]);
        *(uint4*)&Xb[i] = o.u4;
    } else if (bid < 2816) {
        const int u = bid - 2048;
        transpose_tile(Wqkv, Wqkvt, CDIM, 3 * CDIM, (u & 15) * 64, (u >> 4) * 64, tile);
    } else {
        const int u = bid - 2816;
        transpose_tile(Wproj, Wprojt, CDIM, CDIM, (u & 15) * 64, (u >> 4) * 64, tile);
    }
}

// ---------------------------------------------------------------------------
// m97-style GEMM core (kept for proj): C[128x128] = A[M,K] * Bt[N,K]^T
// ---------------------------------------------------------------------------
__device__ __forceinline__ void gemm128_core(
    const unsigned short* __restrict__ A,
    const unsigned short* __restrict__ Bt,
    int K, int m0, int n0,
    unsigned short* As, unsigned short* Bs, f32x4 acc[4][4])
{
    const int tid = threadIdx.x;
    const int w = tid >> 6, lane = tid & 63;
    const int ln = lane & 15, quad = lane >> 4;
    const int wm = w >> 1, wn = w & 1;
    const int lr = lane >> 3;        // 0..7
    const int lc = (lane & 7) * 8;   // col start (elems)

    for (int kb = 0; kb < K; kb += 64) {
        __syncthreads();
#pragma unroll
        for (int i = 0; i < 4; ++i) {
            async_copy16(&A[(size_t)(m0 + w * 32 + i * 8 + lr) * K + kb + lc],
                         &As[(w * 32 + i * 8) * 64]);
            async_copy16(&Bt[(size_t)(n0 + w * 32 + i * 8 + lr) * K + kb + lc],
                         &Bs[(w * 32 + i * 8) * 64]);
        }
        __syncthreads();
#pragma unroll
        for (int kk = 0; kk < 2; ++kk) {
            U16x8 af[4], bff[4];
#pragma unroll
            for (int i = 0; i < 4; ++i)
                af[i].u4 = *(const uint4*)&As[(wm * 64 + i * 16 + ln) * 64 + kk * 32 + quad * 8];
#pragma unroll
            for (int j = 0; j < 4; ++j)
                bff[j].u4 = *(const uint4*)&Bs[(wn * 64 + j * 16 + ln) * 64 + kk * 32 + quad * 8];
#pragma unroll
            for (int i = 0; i < 4; ++i)
#pragma unroll
                for (int j = 0; j < 4; ++j)
                    acc[i][j] = __builtin_amdgcn_mfma_f32_16x16x32_bf16(af[i].b, bff[j].b, acc[i][j], 0, 0, 0);
        }
    }
}

// ---------------------------------------------------------------------------
// 256x256 8-phase counted-vmcnt GEMM (T2+T3+T4+T5), fused QKV epilogue.
// Q slice pre-scaled by 0.125 (folds 1/sqrt(hd) out of flash; R9-verified).
// ---------------------------------------------------------------------------
__device__ __forceinline__ void stageA(const unsigned short* __restrict__ A,
                                       unsigned short* buf,
                                       int m0, int t, int unit, int w, int lane)
{
#pragma unroll
    for (int s = 0; s < 2; ++s) {
        const int r0 = s * 128 + unit * 64 + w * 8;          // wave-uniform
        const int row = r0 + (lane >> 3);
        const int col = (16 * (lane & 7)) ^ ((row & 4) ? 32 : 0);  // bytes, pre-swizzled src
        const unsigned short* src = A + (size_t)(m0 + row) * CDIM + t * 64 + (col >> 1);
        async_copy16(src, buf + r0 * 64);                    // linear LDS dest
    }
}

__device__ __forceinline__ void stageB(const unsigned short* __restrict__ B,
                                       unsigned short* buf,
                                       int n0, int t, int unit, int w, int lane)
{
#pragma unroll
    for (int s = 0; s < 2; ++s) {
        const int slice = s * 8 + w;
        const int r0 = (slice >> 2) * 64 + unit * 32 + (slice & 3) * 8;  // wave-uniform
        const int row = r0 + (lane >> 3);
        const int col = (16 * (lane & 7)) ^ ((row & 4) ? 32 : 0);
        const unsigned short* src = B + (size_t)(n0 + row) * CDIM + t * 64 + (col >> 1);
        async_copy16(src, buf + r0 * 64);
    }
}

__device__ __forceinline__ void readA(U16x8 af[4][2], const unsigned short* buf,
                                      int wm, int qm, int ln, int quad)
{
#pragma unroll
    for (int i = 0; i < 4; ++i) {
        const int row = wm * 128 + qm * 64 + i * 16 + ln;
        const int sw = (row & 4) ? 32 : 0;
#pragma unroll
        for (int kk = 0; kk < 2; ++kk) {
            const int byt = row * 128 + ((kk * 64 + quad * 16) ^ sw);
            af[i][kk].u4 = *(const uint4*)((const char*)buf + byt);
        }
    }
}

__device__ __forceinline__ void readB(U16x8 bf[2][2], const unsigned short* buf,
                                      int wn, int qn, int ln, int quad)
{
#pragma unroll
    for (int jj = 0; jj < 2; ++jj) {
        const int row = wn * 64 + qn * 32 + jj * 16 + ln;
        const int sw = (row & 4) ? 32 : 0;
#pragma unroll
        for (int kk = 0; kk < 2; ++kk) {
            const int byt = row * 128 + ((kk * 64 + quad * 16) ^ sw);
            bf[jj][kk].u4 = *(const uint4*)((const char*)buf + byt);
        }
    }
}

template<int QM, int QN>
__device__ __forceinline__ void mfma16(f32x4 acc[8][4], const U16x8 af[4][2],
                                       const U16x8 bf[2][2])
{
    __builtin_amdgcn_s_setprio(1);
#pragma unroll
    for (int i = 0; i < 4; ++i)
#pragma unroll
        for (int jj = 0; jj < 2; ++jj)
#pragma unroll
            for (int kk = 0; kk < 2; ++kk)
                acc[QM * 4 + i][QN * 2 + jj] = __builtin_amdgcn_mfma_f32_16x16x32_bf16(
                    af[i][kk].b, bf[jj][kk].b, acc[QM * 4 + i][QN * 2 + jj], 0, 0, 0);
    __builtin_amdgcn_s_setprio(0);
}

__global__ __launch_bounds__(512) void qkv8(
    const unsigned short* __restrict__ Xb,    // [4096,1024] bf16
    const unsigned short* __restrict__ Wt,    // [3072,1024] bf16 (W^T; V rows at 2048)
    const float* __restrict__ bias,           // [3072]
    unsigned short* __restrict__ Qp,
    unsigned short* __restrict__ Kp,
    unsigned short* __restrict__ Vtp)         // [B,1024,T]
{
    __shared__ __align__(1024) unsigned short smem[4][16384];  // Abuf0,Abuf1,Bbuf0,Bbuf1
    unsigned short* Ab0 = smem[0];
    unsigned short* Ab1 = smem[1];
    unsigned short* Bb0 = smem[2];
    unsigned short* Bb1 = smem[3];

    const int tid = threadIdx.x;
    const int w = tid >> 6, lane = tid & 63;
    const int ln = lane & 15, quad = lane >> 4;
    const int wm = w >> 2, wn = w & 3;

    // bijective XCD swizzle (192 % 8 == 0): 24 consecutive tiles per XCD
    const int bid = blockIdx.x;
    const int swz = (bid & 7) * 24 + (bid >> 3);
    const int nt = swz % 12, mt = swz / 12;
    const int m0 = mt * 256, n0 = nt * 256;

    f32x4 acc[8][4];
#pragma unroll
    for (int i = 0; i < 8; ++i)
#pragma unroll
        for (int j = 0; j < 4; ++j) acc[i][j] = (f32x4){0.f, 0.f, 0.f, 0.f};

    // ---- prologue: 7 units (tile 0 complete + tile 1 A0/B0/B1), depth-3 pipe
    stageA(Xb, Ab0, m0, 0, 0, w, lane);
    stageB(Wt, Bb0, n0, 0, 0, w, lane);
    stageB(Wt, Bb0, n0, 0, 1, w, lane);
    stageA(Xb, Ab0, m0, 0, 1, w, lane);
    stageA(Xb, Ab1, m0, 1, 0, w, lane);
    stageB(Wt, Bb1, n0, 1, 0, w, lane);
    stageB(Wt, Bb1, n0, 1, 1, w, lane);
    VMC6();            // oldest 4 units (= tile 0) landed
    BAR();

    U16x8 af[4][2], bq0[2][2], bq1[2][2];

    // ---- main loop: 7 iters x 2 K-tiles; tiles 0..13
    for (int j = 0; j < 7; ++j) {
        const int e = 2 * j, o = 2 * j + 1;
        // P1: quad(0,0) of tile e  | stage A1(o) -> buf1
        readA(af, Ab0, wm, 0, ln, quad);
        readB(bq0, Bb0, wn, 0, ln, quad);
        stageA(Xb, Ab1, m0, o, 1, w, lane);
        BAR(); LGKM0();
        mfma16<0, 0>(acc, af, bq0);
        LGKM0(); BAR();
        // P2: quad(0,1)            | stage A0(e+2) -> buf0
        readB(bq1, Bb0, wn, 1, ln, quad);
        stageA(Xb, Ab0, m0, e + 2, 0, w, lane);
        BAR(); LGKM0();
        mfma16<0, 1>(acc, af, bq1);
        LGKM0(); BAR();
        // P3: quad(1,0)            | stage B0(e+2)
        readA(af, Ab0, wm, 1, ln, quad);
        stageB(Wt, Bb0, n0, e + 2, 0, w, lane);
        BAR(); LGKM0();
        mfma16<1, 0>(acc, af, bq0);
        LGKM0(); BAR();
        // P4: quad(1,1)            | stage B1(e+2) ; counted wait
        stageB(Wt, Bb0, n0, e + 2, 1, w, lane);
        BAR();
        mfma16<1, 1>(acc, af, bq1);
        VMC6(); BAR();
        // P5: quad(0,0) of tile o  | stage A1(e+2) -> buf0
        readA(af, Ab1, wm, 0, ln, quad);
        readB(bq0, Bb1, wn, 0, ln, quad);
        stageA(Xb, Ab0, m0, e + 2, 1, w, lane);
        BAR(); LGKM0();
        mfma16<0, 0>(acc, af, bq0);
        LGKM0(); BAR();
        // P6: quad(0,1)            | stage A0(o+2) -> buf1
        readB(bq1, Bb1, wn, 1, ln, quad);
        stageA(Xb, Ab1, m0, o + 2, 0, w, lane);
        BAR(); LGKM0();
        mfma16<0, 1>(acc, af, bq1);
        LGKM0(); BAR();
        // P7: quad(1,0)            | stage B0(o+2)
        readA(af, Ab1, wm, 1, ln, quad);
        stageB(Wt, Bb1, n0, o + 2, 0, w, lane);
        BAR(); LGKM0();
        mfma16<1, 0>(acc, af, bq0);
        LGKM0(); BAR();
        // P8: quad(1,1)            | stage B1(o+2) ; counted wait
        stageB(Wt, Bb1, n0, o + 2, 1, w, lane);
        BAR();
        mfma16<1, 1>(acc, af, bq1);
        VMC6(); BAR();
    }

    // ---- epilogue: tiles 14 (buf0), 15 (buf1); stage last unit then drain
    stageA(Xb, Ab1, m0, 15, 1, w, lane);
    VMC0(); BAR();

    readA(af, Ab0, wm, 0, ln, quad);
    readB(bq0, Bb0, wn, 0, ln, quad);
    readB(bq1, Bb0, wn, 1, ln, quad);
    mfma16<0, 0>(acc, af, bq0);
    mfma16<0, 1>(acc, af, bq1);
    readA(af, Ab0, wm, 1, ln, quad);
    mfma16<1, 0>(acc, af, bq0);
    mfma16<1, 1>(acc, af, bq1);

    readA(af, Ab1, wm, 0, ln, quad);
    readB(bq0, Bb1, wn, 0, ln, quad);
    readB(bq1, Bb1, wn, 1, ln, quad);
    mfma16<0, 0>(acc, af, bq0);
    mfma16<0, 1>(acc, af, bq1);
    readA(af, Ab1, wm, 1, ln, quad);
    mfma16<1, 0>(acc, af, bq0);
    mfma16<1, 1>(acc, af, bq1);

    // ---- C epilogue: n-tile selects Q / K / V^T (BN=256 divides 1024)
    const int which = n0 >> 10;
    float bv[4];
#pragma unroll
    for (int jj = 0; jj < 4; ++jj) bv[jj] = bias[n0 + wn * 64 + jj * 16 + ln];

    if (which < 2) {
        unsigned short* dst = (which == 0) ? Qp : Kp;
        const float qsc = (which == 0) ? 0.125f : 1.0f;   // fold 1/sqrt(hd) into Q
#pragma unroll
        for (int jj = 0; jj < 4; ++jj) {
            const int n = n0 + wn * 64 + jj * 16 + ln;
            const int h = (n >> 6) & 15, d = n & 63;
#pragma unroll
            for (int i = 0; i < 8; ++i)
#pragma unroll
                for (int r = 0; r < 4; ++r) {
                    const int m = m0 + wm * 128 + i * 16 + quad * 4 + r;
                    const int b = m >> 11, tt = m & 2047;
                    dst[(((size_t)(b * NHEAD + h) * T_SEQ) + tt) * HD + d] =
                        f2bf((acc[i][jj][r] + bv[jj]) * qsc);
                }
        }
    } else {
#pragma unroll
        for (int jj = 0; jj < 4; ++jj) {
            const int n = n0 + wn * 64 + jj * 16 + ln;
            const int c = n - 2048;                       // channel h*64+d
#pragma unroll
            for (int i = 0; i < 8; ++i) {
                const int m00 = m0 + wm * 128 + i * 16 + quad * 4;  // 4 consecutive tokens
                const int b = m00 >> 11, tt = m00 & 2047;
                ushort4 pk;
                pk.x = f2bf(acc[i][jj][0] + bv[jj]);
                pk.y = f2bf(acc[i][jj][1] + bv[jj]);
                pk.z = f2bf(acc[i][jj][2] + bv[jj]);
                pk.w = f2bf(acc[i][jj][3] + bv[jj]);
                *(ushort4*)&Vtp[(size_t)(b * 1024 + c) * T_SEQ + tt] = pk;
            }
        }
    }
}

// ---------------------------------------------------------------------------
// Kernel: proj GEMM -> fp32 out.  n-tiles on blockIdx.x (XCD L2).
// ---------------------------------------------------------------------------
__global__ __launch_bounds__(256) void proj_gemm(
    const unsigned short* __restrict__ Yin,   // [4096,1024] bf16
    const unsigned short* __restrict__ Wt,    // [1024,1024] bf16 (W^T)
    const float* __restrict__ bias,           // [1024]
    float* __restrict__ out)                  // [4096,1024] fp32
{
    __shared__ unsigned short As[128 * 64];
    __shared__ unsigned short Bs[128 * 64];
    const int m0 = blockIdx.y * 128;
    const int n0 = blockIdx.x * 128;

    f32x4 acc[4][4];
#pragma unroll
    for (int i = 0; i < 4; ++i)
#pragma unroll
        for (int j = 0; j < 4; ++j) acc[i][j] = (f32x4){0.f, 0.f, 0.f, 0.f};

    gemm128_core(Yin, Wt, CDIM, m0, n0, As, Bs, acc);

    const int tid = threadIdx.x;
    const int w = tid >> 6, lane = tid & 63;
    const int ln = lane & 15, quad = lane >> 4;
    const int wm = w >> 1, wn = w & 1;

#pragma unroll
    for (int j = 0; j < 4; ++j) {
        const int n = n0 + wn * 64 + j * 16 + ln;
        const float bv = bias[n];
#pragma unroll
        for (int i = 0; i < 4; ++i)
#pragma unroll
            for (int r = 0; r < 4; ++r) {
                const int m = m0 + wm * 64 + i * 16 + quad * 4 + r;
                out[(size_t)m * CDIM + n] = acc[i][j][r] + bv;
            }
    }
}

// ---------------------------------------------------------------------------
// Flash attention, R8-verified structure (54 us, VGPR 120, no spill):
//   single-width 64-token k-steps, global split-k.
//   grid (32 bh, 24 slots):
//     y<16 : SPLIT blocks: qb = 15-(y>>1) in 8..15, sgk = y&1; tiles
//            j = sgk, sgk+2, ... ; write unnormalized partials.
//     y>=16: UNSPLIT: qb = 23-y in 0..7; store Y directly.
//   Only delta vs R8: Q is pre-scaled by 0.125 in qkv8, so the mask
//   path is a pure add (no per-element 0.125 multiply).
//   R9 lesson: do NOT double prefetch width — kr[4]/vr[4] loop-carried
//   state triggers scratch demotion (VGPR 120->84, WRITE_SIZE 140 MB).
// ---------------------------------------------------------------------------

// ushort index in a [64][64] bf16 tile; slot = 16B-chunk 0..7, XOR-swizzled
__device__ __forceinline__ int swz(int row, int slot) {
    return row * 64 + ((slot ^ (row & 7)) << 3);
}

__global__ __launch_bounds__(256) void flash_attn32(
    const unsigned short* __restrict__ Qp,   // [BH, T, 64]  (Q pre-scaled 0.125)
    const unsigned short* __restrict__ Kp,   // [BH, T, 64]
    const unsigned short* __restrict__ Vtp,  // [BH, 64, T]
    const int* __restrict__ mask,            // [B, T]
    unsigned short* __restrict__ Y,          // [B*T, 1024] bf16
    unsigned short* __restrict__ Po,         // [32*8*2, 128, 64] bf16 partial O
    float* __restrict__ Pm,                  // [32*8*2, 128] partial m
    float* __restrict__ Pl)                  // [32*8*2, 128] partial l
{
    __shared__ unsigned short Ks[64 * 64];   // swizzled
    __shared__ unsigned short Vs[64 * 64];   // swizzled (V^T: rows=d)
    __shared__ float mask_arr[64];           // permuted to reg order
    __shared__ float als[4][32];             // per-warp alpha / 1/l broadcast
    __shared__ int flagu;                    // 0 = all 64 tokens valid this tile

    const int bh = blockIdx.x;
    const int y = blockIdx.y;
    int qb, j0, jstep;
    bool split;
    if (y < 16) { qb = 15 - (y >> 1); j0 = y & 1; jstep = 2; split = true; }
    else        { qb = 23 - y;        j0 = 0;     jstep = 1; split = false; }
    const int sgk = y & 1;                   // segment id (split only)

    const int b = bh >> 4, h = bh & 15;
    const int tid = threadIdx.x;
    const int w = tid >> 6, lane = tid & 63;
    const int l31 = lane & 31, hi = lane >> 5;
    const int row8 = tid >> 3, seg = tid & 7;
    const size_t base = (size_t)bh * T_SEQ * HD;
    const int qB = qb * 128;
    const int qw0 = qB + w * 32;
    const int qv = qw0 + l31;                // this lane's softmax q-row
    const int jlast = 2 * qb + 1;

    // Q fragments: qf[c] = Q[qv][c*16 + hi*8 .. +8]  (B-operand of swapped QK^T)
    U16x8 qf[4];
    {
        const unsigned short* qrow = &Qp[base + (size_t)qv * HD];
#pragma unroll
        for (int c = 0; c < 4; ++c)
            qf[c].u4 = *(const uint4*)&qrow[c * 16 + hi * 8];
    }

    f32x16 oA0, oA1;
#pragma unroll
    for (int r = 0; r < 16; ++r) { oA0[r] = 0.f; oA1[r] = 0.f; }
    float m_r = -3.0e38f, mL = 0.f, l_r = 0.f;

    // register prefetch of tile j0
    uint4 kr0, kr1, vr0, vr1;
    float mf = 0.f;
    {
        const unsigned short* kp0 = &Kp[base + (size_t)(j0 * 64 + row8) * HD + seg * 8];
        kr0 = *(const uint4*)kp0;
        kr1 = *(const uint4*)(kp0 + 32 * HD);
        const unsigned short* vp0 = &Vtp[base + (size_t)row8 * T_SEQ + j0 * 64 + seg * 8];
        vr0 = *(const uint4*)vp0;
        vr1 = *(const uint4*)(vp0 + 32 * T_SEQ);
        if (tid < 64) mf = mask[b * T_SEQ + j0 * 64 + tid] ? 0.f : -1.0e30f;
    }

    for (int j = j0; j <= jlast; j += jstep) {
        __syncthreads();
        *(uint4*)&Ks[swz(row8, seg)]      = kr0;
        *(uint4*)&Ks[swz(row8 + 32, seg)] = kr1;
        *(uint4*)&Vs[swz(row8, seg)]      = vr0;
        *(uint4*)&Vs[swz(row8 + 32, seg)] = vr1;
        if (w == 0) {
            // mask value for token k=lane -> reg-order slot (hi,kb,g,k&3)
            const int k = lane;
            const int idx = ((k >> 2) & 1) * 32 + (k >> 5) * 16 + ((k & 31) >> 3) * 4 + (k & 3);
            mask_arr[idx] = mf;
            const unsigned long long bb = __ballot(mf == 0.f);
            if (lane == 0) flagu = (bb == 0xFFFFFFFFFFFFFFFFull) ? 0 : 1;
        }
        __syncthreads();

        const int jn = j + jstep;
        if (jn <= jlast) {   // prefetch next tile of this segment
            const unsigned short* kp0 = &Kp[base + (size_t)(jn * 64 + row8) * HD + seg * 8];
            kr0 = *(const uint4*)kp0;
            kr1 = *(const uint4*)(kp0 + 32 * HD);
            const unsigned short* vp0 = &Vtp[base + (size_t)row8 * T_SEQ + jn * 64 + seg * 8];
            vr0 = *(const uint4*)vp0;
            vr1 = *(const uint4*)(vp0 + 32 * T_SEQ);
            if (tid < 64) mf = mask[b * T_SEQ + jn * 64 + tid] ? 0.f : -1.0e30f;
        }

        const bool skipw = (j * 64 > qw0 + 31);
        if (!skipw) {
            const bool edge = (j * 64 + 63 > qw0);
            const int anymask = flagu;

            // ---- S^T = K Q^T  (two 32-k halves; Q pre-scaled)
            f32x16 sc0, sc1;
#pragma unroll
            for (int r = 0; r < 16; ++r) { sc0[r] = 0.f; sc1[r] = 0.f; }
#pragma unroll
            for (int c = 0; c < 4; ++c) {
                U16x8 ka0, ka1;
                const int r0 = l31, r1 = 32 + l31;
                ka0.u4 = *(const uint4*)&Ks[r0 * 64 + (((2 * c + hi) ^ (r0 & 7)) << 3)];
                ka1.u4 = *(const uint4*)&Ks[r1 * 64 + (((2 * c + hi) ^ (r1 & 7)) << 3)];
                sc0 = __builtin_amdgcn_mfma_f32_32x32x16_bf16(ka0.b, qf[c].b, sc0, 0, 0, 0);
                sc1 = __builtin_amdgcn_mfma_f32_32x32x16_bf16(ka1.b, qf[c].b, sc1, 0, 0, 0);
            }

            // ---- pad mask (pure add; scale already folded into Q)
            if (anymask) {
#pragma unroll
                for (int g = 0; g < 4; ++g) {
                    const f32x4 m0v = *(const f32x4*)&mask_arr[hi * 32 + g * 4];
                    const f32x4 m1v = *(const f32x4*)&mask_arr[hi * 32 + 16 + g * 4];
#pragma unroll
                    for (int t = 0; t < 4; ++t) {
                        sc0[g * 4 + t] += m0v[t];
                        sc1[g * 4 + t] += m1v[t];
                    }
                }
            }
            // ---- causal edge: k_global > q -> -inf
            if (edge) {
#pragma unroll
                for (int r = 0; r < 16; ++r) {
                    const int krow = (r & 3) + 8 * (r >> 2) + 4 * hi;
                    if (j * 64 + krow > qv)      sc0[r] = -1.0e30f;
                    if (j * 64 + 32 + krow > qv) sc1[r] = -1.0e30f;
                }
            }

            // ---- tile max (in-lane 32 values, then lane<->lane+32 merge)
            float tm = -3.0e38f;
#pragma unroll
            for (int r = 0; r < 16; ++r)
                tm = fmaxf(tm, fmaxf(sc0[r], sc1[r]));
            tm = fmaxf(tm, __shfl_xor(tm, 32));

            // ---- defer-max: rescale only if max grew > THR
            if (__any(tm > m_r + 8.f)) {
                const float mn = fmaxf(m_r, tm);
                const float a = __builtin_amdgcn_exp2f((m_r - mn) * LOG2E);
                m_r = mn; mL = mn * LOG2E;
                l_r *= a;
                if (hi == 0) als[w][l31] = a;      // alpha indexed by q
                f32x4 av[4];
#pragma unroll
                for (int g = 0; g < 4; ++g)
                    av[g] = *(const f32x4*)&als[w][g * 8 + hi * 4];
#pragma unroll
                for (int r = 0; r < 16; ++r) {
                    const float aa = av[r >> 2][r & 3];
                    oA0[r] *= aa; oA1[r] *= aa;
                }
            }

            // ---- exp + per-lane partial sum
            float ps = 0.f;
#pragma unroll
            for (int r = 0; r < 16; ++r) {
                const float p0 = __builtin_amdgcn_exp2f(fmaf(sc0[r], LOG2E, -mL));
                const float p1 = __builtin_amdgcn_exp2f(fmaf(sc1[r], LOG2E, -mL));
                sc0[r] = p0; sc1[r] = p1;
                ps += p0 + p1;
            }
            l_r += ps;

            // ---- P -> bf16 A-frags (cvt_pk + permlane32_swap) ; O += P V
#pragma unroll
            for (int c = 0; c < 4; ++c) {
                const int rb = (c & 1) * 8;
                unsigned int x0, y0, x1, y1;
                if (c < 2) {
                    x0 = cvtpk_bf16(sc0[rb + 0], sc0[rb + 1]);
                    y0 = cvtpk_bf16(sc0[rb + 4], sc0[rb + 5]);
                    x1 = cvtpk_bf16(sc0[rb + 2], sc0[rb + 3]);
                    y1 = cvtpk_bf16(sc0[rb + 6], sc0[rb + 7]);
                } else {
                    x0 = cvtpk_bf16(sc1[rb + 0], sc1[rb + 1]);
                    y0 = cvtpk_bf16(sc1[rb + 4], sc1[rb + 5]);
                    x1 = cvtpk_bf16(sc1[rb + 2], sc1[rb + 3]);
                    y1 = cvtpk_bf16(sc1[rb + 6], sc1[rb + 7]);
                }
                plane32swap(x0, y0);   // x0 -> au[0] (j=0,1), y0 -> au[2] (j=4,5)
                plane32swap(x1, y1);   // x1 -> au[1] (j=2,3), y1 -> au[3] (j=6,7)
                U16x8 pa;
                pa.u4 = make_uint4(x0, x1, y0, y1);
                {
                    const int vr_0 = l31, vr_1 = 32 + l31;
                    U16x8 vb0, vb1;
                    vb0.u4 = *(const uint4*)&Vs[vr_0 * 64 + (((2 * c + hi) ^ (vr_0 & 7)) << 3)];
                    vb1.u4 = *(const uint4*)&Vs[vr_1 * 64 + (((2 * c + hi) ^ (vr_1 & 7)) << 3)];
                    oA0 = __builtin_amdgcn_mfma_f32_32x32x16_bf16(pa.b, vb0.b, oA0, 0, 0, 0);
                    oA1 = __builtin_amdgcn_mfma_f32_32x32x16_bf16(pa.b, vb1.b, oA1, 0, 0, 0);
                }
            }
        }
    }

    // ---- hi-merge of the row-sum partial (each lane covers its hi-half)
    const float lt = l_r + __shfl_xor(l_r, 32);

    if (split) {
        // ---- write unnormalized partials (O-layout rows, lane-q m/l)
        const int pidx = (bh * 8 + (qb - 8)) * 2 + sgk;
        if (hi == 0) {
            Pm[pidx * 128 + w * 32 + l31] = m_r;
            Pl[pidx * 128 + w * 32 + l31] = lt;
        }
#pragma unroll
        for (int r = 0; r < 16; ++r) {
            const int qlc = w * 32 + (r & 3) + 8 * (r >> 2) + 4 * hi;
            Po[(size_t)pidx * 8192 + qlc * 64 + l31]      = f2bf(oA0[r]);
            Po[(size_t)pidx * 8192 + qlc * 64 + 32 + l31] = f2bf(oA1[r]);
        }
    } else {
        // ---- normalize + store
        if (hi == 0) als[w][l31] = 1.0f / lt;
        f32x4 lv[4];
#pragma unroll
        for (int g = 0; g < 4; ++g)
            lv[g] = *(const f32x4*)&als[w][g * 8 + hi * 4];
#pragma unroll
        for (int r = 0; r < 16; ++r) {
            const int q = qw0 + (r & 3) + 8 * (r >> 2) + 4 * hi;
            const float sl = lv[r >> 2][r & 3];
            const size_t row = (size_t)(b * T_SEQ + q);
            Y[row * CDIM + h * HD + l31]      = f2bf(oA0[r] * sl);
            Y[row * CDIM + h * HD + 32 + l31] = f2bf(oA1[r] * sl);
        }
    }
}

// ---------------------------------------------------------------------------
// Merge the two k-segments of each split (bh, qb>=8) chunk.
//   O = (f0*O0 + f1*O1) / (f0*l0 + f1*l1),  f_i = exp(m_i - max(m0,m1)).
//   grid 1024 = 32 bh x 8 qc x 4 parts; thread -> (q row, 8 d cols).
// ---------------------------------------------------------------------------
__global__ __launch_bounds__(256) void merge_attn(
    const unsigned short* __restrict__ Po,
    const float* __restrict__ Pm, const float* __restrict__ Pl,
    unsigned short* __restrict__ Y)
{
    const int u = blockIdx.x;
    const int bh = u & 31;
    const int v = u >> 5;                 // 0..31
    const int qc = v >> 2, part = v & 3;
    const int tid = threadIdx.x;
    const int ql = part * 32 + (tid >> 3);
    const int d0 = (tid & 7) * 8;
    const int b = bh >> 4, h = bh & 15;
    const int i0 = (bh * 8 + qc) * 2, i1 = i0 + 1;

    const float m0 = Pm[i0 * 128 + ql], m1 = Pm[i1 * 128 + ql];
    const float l0 = Pl[i0 * 128 + ql], l1 = Pl[i1 * 128 + ql];
    const float M = fmaxf(m0, m1);
    const float f0 = __builtin_amdgcn_exp2f((m0 - M) * LOG2E);
    const float f1 = __builtin_amdgcn_exp2f((m1 - M) * LOG2E);
    const float inv = 1.0f / (f0 * l0 + f1 * l1);

    U16x8 a, c, o;
    a.u4 = *(const uint4*)&Po[(size_t)i0 * 8192 + ql * 64 + d0];
    c.u4 = *(const uint4*)&Po[(size_t)i1 * 8192 + ql * 64 + d0];
#pragma unroll
    for (int j = 0; j < 8; ++j)
        o.s[j] = f2bf((f0 * bf2f(a.s[j]) + f1 * bf2f(c.s[j])) * inv);

    const int q = 1024 + qc * 128 + ql;
    *(uint4*)&Y[(size_t)(b * T_SEQ + q) * CDIM + h * HD + d0] = o.u4;
}

// ---------------------------------------------------------------------------
extern "C" void kernel_launch(void* const* d_in, const int* in_sizes, int n_in,
                              void* d_out, int out_size, void* d_ws, size_t ws_size,
                              hipStream_t stream)
{
    const float* X     = (const float*)d_in[0];
    const int*   mask  = (const int*)d_in[1];
    const float* Wqkv  = (const float*)d_in[2];
    const float* bqkv  = (const float*)d_in[3];
    const float* Wproj = (const float*)d_in[4];
    const float* bproj = (const float*)d_in[5];
    float* out = (float*)d_out;

    const size_t per = (size_t)2 * NHEAD * T_SEQ * HD;   // 4,194,304 elems
    unsigned short* Qp     = (unsigned short*)d_ws;
    unsigned short* Kp     = Qp + per;
    unsigned short* Vtp    = Kp + per;
    unsigned short* Xb     = Vtp + per;                  // aliased: Yp reuses Xb
    unsigned short* Yp     = Xb;                         // X consumed before Y written
    unsigned short* Wqkvt  = Xb + per;                   // [3072,1024]
    unsigned short* Wprojt = Wqkvt + (size_t)3 * CDIM * CDIM;  // [1024,1024]
    unsigned short* Po     = Wprojt + (size_t)CDIM * CDIM;     // [512,128,64] bf16
    float*          Pm     = (float*)(Po + (size_t)512 * 8192);
    float*          Pl     = Pm + 512 * 128;

    prep<<<3072, 256, 0, stream>>>(X, Xb, Wqkv, Wqkvt, Wproj, Wprojt);
    qkv8<<<192, 512, 0, stream>>>(Xb, Wqkvt, bqkv, Qp, Kp, Vtp);
    flash_attn32<<<dim3(2 * NHEAD, 24), 256, 0, stream>>>(Qp, Kp, Vtp, mask, Yp, Po, Pm, Pl);
    merge_attn<<<1024, 256, 0, stream>>>(Po, Pm, Pl, Yp);
    proj_gemm<<<dim3(8, 32), 256, 0, stream>>>(Yp, Wprojt, bproj, out);
}

// Round 11
// 209.456 us; speedup vs baseline: 1.1096x; 1.0251x over previous
//
#include <hip/hip_runtime.h>

#define T_SEQ 2048
#define NHEAD 16
#define HD 64
#define CDIM 1024

typedef __bf16 bf16x8 __attribute__((ext_vector_type(8)));
typedef float f32x4 __attribute__((ext_vector_type(4)));
typedef float f32x16 __attribute__((ext_vector_type(16)));

union U16x8 { uint4 u4; unsigned short s[8]; bf16x8 b; };

__device__ __forceinline__ float bf2f(unsigned short u) {
    return __uint_as_float(((unsigned int)u) << 16);
}
__device__ __forceinline__ unsigned short f2bf(float f) {
    unsigned int u = __float_as_uint(f);
    u += 0x7fffu + ((u >> 16) & 1u);   // round-to-nearest-even
    return (unsigned short)(u >> 16);
}
__device__ __forceinline__ U16x8 load8f(const float* __restrict__ p) {
    U16x8 r;
    float4 f0 = *(const float4*)p;
    float4 f1 = *(const float4*)(p + 4);
    r.s[0] = f2bf(f0.x); r.s[1] = f2bf(f0.y); r.s[2] = f2bf(f0.z); r.s[3] = f2bf(f0.w);
    r.s[4] = f2bf(f1.x); r.s[5] = f2bf(f1.y); r.s[6] = f2bf(f1.z); r.s[7] = f2bf(f1.w);
    return r;
}

// async global->LDS, 16 B per lane; LDS dest = wave-uniform base + lane*16
__device__ __forceinline__ void async_copy16(const unsigned short* g, unsigned short* l) {
    __builtin_amdgcn_global_load_lds(
        (const __attribute__((address_space(1))) unsigned int*)g,
        (__attribute__((address_space(3))) unsigned int*)l, 16, 0, 0);
}

#define LOG2E 1.442695040f

// raw barrier / counted waits (NEVER __syncthreads in the 8-phase loop: it drains vmcnt)
#define BAR()    asm volatile("s_barrier" ::: "memory")
#define LGKM0()  asm volatile("s_waitcnt lgkmcnt(0)" ::: "memory")
#define VMC6()   asm volatile("s_waitcnt vmcnt(6)" ::: "memory")
#define VMC0()   asm volatile("s_waitcnt vmcnt(0)" ::: "memory")

// v_cvt_pk_bf16_f32: D.lo = bf16(lo), D.hi = bf16(hi)
__device__ __forceinline__ unsigned int cvtpk_bf16(float lo, float hi) {
    unsigned int r;
    asm("v_cvt_pk_bf16_f32 %0, %1, %2" : "=v"(r) : "v"(lo), "v"(hi));
    return r;
}
// x' = {x[0:31], y[0:31]}, y' = {x[32:63], y[32:63]}
__device__ __forceinline__ void plane32swap(unsigned int &x, unsigned int &y) {
    asm("v_permlane32_swap_b32 %0, %1" : "+v"(x), "+v"(y));
}

// ---------------------------------------------------------------------------
// Merged prep kernel (R7-verified): conv + both weight transposes.
// ---------------------------------------------------------------------------
__device__ __forceinline__ void transpose_tile(
    const float* __restrict__ in, unsigned short* __restrict__ out,
    int R, int C, int r0, int c0, float tile[64][65])
{
    const int tid = threadIdx.x;
    const int rr = tid >> 4;
    const int cc = (tid & 15) * 4;
#pragma unroll
    for (int p = 0; p < 4; ++p) {
        float4 v = *(const float4*)&in[(size_t)(r0 + p * 16 + rr) * C + c0 + cc];
        tile[p * 16 + rr][cc] = v.x;
        tile[p * 16 + rr][cc + 1] = v.y;
        tile[p * 16 + rr][cc + 2] = v.z;
        tile[p * 16 + rr][cc + 3] = v.w;
    }
    __syncthreads();
    const int n = tid >> 2;
    const int s = (tid & 3) * 8;
#pragma unroll
    for (int p = 0; p < 2; ++p) {
        const int k = s + p * 32;
        U16x8 o;
#pragma unroll
        for (int j = 0; j < 8; ++j) o.s[j] = f2bf(tile[k + j][n]);
        *(uint4*)&out[(size_t)(c0 + n) * R + r0 + k] = o.u4;
    }
}

__global__ __launch_bounds__(256) void prep(
    const float* __restrict__ X,     unsigned short* __restrict__ Xb,
    const float* __restrict__ Wqkv,  unsigned short* __restrict__ Wqkvt,
    const float* __restrict__ Wproj, unsigned short* __restrict__ Wprojt)
{
    __shared__ float tile[64][65];
    const int bid = blockIdx.x;
    if (bid < 2048) {
        const int i = (bid * 256 + threadIdx.x) * 8;
        U16x8 o = load8f(&X[i]);
        *(uint4*)&Xb[i] = o.u4;
    } else if (bid < 2816) {
        const int u = bid - 2048;
        transpose_tile(Wqkv, Wqkvt, CDIM, 3 * CDIM, (u & 15) * 64, (u >> 4) * 64, tile);
    } else {
        const int u = bid - 2816;
        transpose_tile(Wproj, Wprojt, CDIM, CDIM, (u & 15) * 64, (u >> 4) * 64, tile);
    }
}

// ---------------------------------------------------------------------------
// m97-style GEMM core (kept for proj): C[128x128] = A[M,K] * Bt[N,K]^T
// ---------------------------------------------------------------------------
__device__ __forceinline__ void gemm128_core(
    const unsigned short* __restrict__ A,
    const unsigned short* __restrict__ Bt,
    int K, int m0, int n0,
    unsigned short* As, unsigned short* Bs, f32x4 acc[4][4])
{
    const int tid = threadIdx.x;
    const int w = tid >> 6, lane = tid & 63;
    const int ln = lane & 15, quad = lane >> 4;
    const int wm = w >> 1, wn = w & 1;
    const int lr = lane >> 3;        // 0..7
    const int lc = (lane & 7) * 8;   // col start (elems)

    for (int kb = 0; kb < K; kb += 64) {
        __syncthreads();
#pragma unroll
        for (int i = 0; i < 4; ++i) {
            async_copy16(&A[(size_t)(m0 + w * 32 + i * 8 + lr) * K + kb + lc],
                         &As[(w * 32 + i * 8) * 64]);
            async_copy16(&Bt[(size_t)(n0 + w * 32 + i * 8 + lr) * K + kb + lc],
                         &Bs[(w * 32 + i * 8) * 64]);
        }
        __syncthreads();
#pragma unroll
        for (int kk = 0; kk < 2; ++kk) {
            U16x8 af[4], bff[4];
#pragma unroll
            for (int i = 0; i < 4; ++i)
                af[i].u4 = *(const uint4*)&As[(wm * 64 + i * 16 + ln) * 64 + kk * 32 + quad * 8];
#pragma unroll
            for (int j = 0; j < 4; ++j)
                bff[j].u4 = *(const uint4*)&Bs[(wn * 64 + j * 16 + ln) * 64 + kk * 32 + quad * 8];
#pragma unroll
            for (int i = 0; i < 4; ++i)
#pragma unroll
                for (int j = 0; j < 4; ++j)
                    acc[i][j] = __builtin_amdgcn_mfma_f32_16x16x32_bf16(af[i].b, bff[j].b, acc[i][j], 0, 0, 0);
        }
    }
}

// ---------------------------------------------------------------------------
// 256x256 8-phase counted-vmcnt GEMM (T2+T3+T4+T5), fused QKV epilogue.
// Q slice pre-scaled by 0.125 (folds 1/sqrt(hd) out of flash; R9-verified).
// ---------------------------------------------------------------------------
__device__ __forceinline__ void stageA(const unsigned short* __restrict__ A,
                                       unsigned short* buf,
                                       int m0, int t, int unit, int w, int lane)
{
#pragma unroll
    for (int s = 0; s < 2; ++s) {
        const int r0 = s * 128 + unit * 64 + w * 8;          // wave-uniform
        const int row = r0 + (lane >> 3);
        const int col = (16 * (lane & 7)) ^ ((row & 4) ? 32 : 0);  // bytes, pre-swizzled src
        const unsigned short* src = A + (size_t)(m0 + row) * CDIM + t * 64 + (col >> 1);
        async_copy16(src, buf + r0 * 64);                    // linear LDS dest
    }
}

__device__ __forceinline__ void stageB(const unsigned short* __restrict__ B,
                                       unsigned short* buf,
                                       int n0, int t, int unit, int w, int lane)
{
#pragma unroll
    for (int s = 0; s < 2; ++s) {
        const int slice = s * 8 + w;
        const int r0 = (slice >> 2) * 64 + unit * 32 + (slice & 3) * 8;  // wave-uniform
        const int row = r0 + (lane >> 3);
        const int col = (16 * (lane & 7)) ^ ((row & 4) ? 32 : 0);
        const unsigned short* src = B + (size_t)(n0 + row) * CDIM + t * 64 + (col >> 1);
        async_copy16(src, buf + r0 * 64);
    }
}

__device__ __forceinline__ void readA(U16x8 af[4][2], const unsigned short* buf,
                                      int wm, int qm, int ln, int quad)
{
#pragma unroll
    for (int i = 0; i < 4; ++i) {
        const int row = wm * 128 + qm * 64 + i * 16 + ln;
        const int sw = (row & 4) ? 32 : 0;
#pragma unroll
        for (int kk = 0; kk < 2; ++kk) {
            const int byt = row * 128 + ((kk * 64 + quad * 16) ^ sw);
            af[i][kk].u4 = *(const uint4*)((const char*)buf + byt);
        }
    }
}

__device__ __forceinline__ void readB(U16x8 bf[2][2], const unsigned short* buf,
                                      int wn, int qn, int ln, int quad)
{
#pragma unroll
    for (int jj = 0; jj < 2; ++jj) {
        const int row = wn * 64 + qn * 32 + jj * 16 + ln;
        const int sw = (row & 4) ? 32 : 0;
#pragma unroll
        for (int kk = 0; kk < 2; ++kk) {
            const int byt = row * 128 + ((kk * 64 + quad * 16) ^ sw);
            bf[jj][kk].u4 = *(const uint4*)((const char*)buf + byt);
        }
    }
}

template<int QM, int QN>
__device__ __forceinline__ void mfma16(f32x4 acc[8][4], const U16x8 af[4][2],
                                       const U16x8 bf[2][2])
{
    __builtin_amdgcn_s_setprio(1);
#pragma unroll
    for (int i = 0; i < 4; ++i)
#pragma unroll
        for (int jj = 0; jj < 2; ++jj)
#pragma unroll
            for (int kk = 0; kk < 2; ++kk)
                acc[QM * 4 + i][QN * 2 + jj] = __builtin_amdgcn_mfma_f32_16x16x32_bf16(
                    af[i][kk].b, bf[jj][kk].b, acc[QM * 4 + i][QN * 2 + jj], 0, 0, 0);
    __builtin_amdgcn_s_setprio(0);
}

__global__ __launch_bounds__(512) void qkv8(
    const unsigned short* __restrict__ Xb,    // [4096,1024] bf16
    const unsigned short* __restrict__ Wt,    // [3072,1024] bf16 (W^T; V rows at 2048)
    const float* __restrict__ bias,           // [3072]
    unsigned short* __restrict__ Qp,
    unsigned short* __restrict__ Kp,
    unsigned short* __restrict__ Vtp)         // [B,1024,T]
{
    __shared__ __align__(1024) unsigned short smem[4][16384];  // Abuf0,Abuf1,Bbuf0,Bbuf1
    unsigned short* Ab0 = smem[0];
    unsigned short* Ab1 = smem[1];
    unsigned short* Bb0 = smem[2];
    unsigned short* Bb1 = smem[3];

    const int tid = threadIdx.x;
    const int w = tid >> 6, lane = tid & 63;
    const int ln = lane & 15, quad = lane >> 4;
    const int wm = w >> 2, wn = w & 3;

    // bijective XCD swizzle (192 % 8 == 0): 24 consecutive tiles per XCD
    const int bid = blockIdx.x;
    const int swz = (bid & 7) * 24 + (bid >> 3);
    const int nt = swz % 12, mt = swz / 12;
    const int m0 = mt * 256, n0 = nt * 256;

    f32x4 acc[8][4];
#pragma unroll
    for (int i = 0; i < 8; ++i)
#pragma unroll
        for (int j = 0; j < 4; ++j) acc[i][j] = (f32x4){0.f, 0.f, 0.f, 0.f};

    // ---- prologue: 7 units (tile 0 complete + tile 1 A0/B0/B1), depth-3 pipe
    stageA(Xb, Ab0, m0, 0, 0, w, lane);
    stageB(Wt, Bb0, n0, 0, 0, w, lane);
    stageB(Wt, Bb0, n0, 0, 1, w, lane);
    stageA(Xb, Ab0, m0, 0, 1, w, lane);
    stageA(Xb, Ab1, m0, 1, 0, w, lane);
    stageB(Wt, Bb1, n0, 1, 0, w, lane);
    stageB(Wt, Bb1, n0, 1, 1, w, lane);
    VMC6();            // oldest 4 units (= tile 0) landed
    BAR();

    U16x8 af[4][2], bq0[2][2], bq1[2][2];

    // ---- main loop: 7 iters x 2 K-tiles; tiles 0..13
    for (int j = 0; j < 7; ++j) {
        const int e = 2 * j, o = 2 * j + 1;
        // P1: quad(0,0) of tile e  | stage A1(o) -> buf1
        readA(af, Ab0, wm, 0, ln, quad);
        readB(bq0, Bb0, wn, 0, ln, quad);
        stageA(Xb, Ab1, m0, o, 1, w, lane);
        BAR(); LGKM0();
        mfma16<0, 0>(acc, af, bq0);
        LGKM0(); BAR();
        // P2: quad(0,1)            | stage A0(e+2) -> buf0
        readB(bq1, Bb0, wn, 1, ln, quad);
        stageA(Xb, Ab0, m0, e + 2, 0, w, lane);
        BAR(); LGKM0();
        mfma16<0, 1>(acc, af, bq1);
        LGKM0(); BAR();
        // P3: quad(1,0)            | stage B0(e+2)
        readA(af, Ab0, wm, 1, ln, quad);
        stageB(Wt, Bb0, n0, e + 2, 0, w, lane);
        BAR(); LGKM0();
        mfma16<1, 0>(acc, af, bq0);
        LGKM0(); BAR();
        // P4: quad(1,1)            | stage B1(e+2) ; counted wait
        stageB(Wt, Bb0, n0, e + 2, 1, w, lane);
        BAR();
        mfma16<1, 1>(acc, af, bq1);
        VMC6(); BAR();
        // P5: quad(0,0) of tile o  | stage A1(e+2) -> buf0
        readA(af, Ab1, wm, 0, ln, quad);
        readB(bq0, Bb1, wn, 0, ln, quad);
        stageA(Xb, Ab0, m0, e + 2, 1, w, lane);
        BAR(); LGKM0();
        mfma16<0, 0>(acc, af, bq0);
        LGKM0(); BAR();
        // P6: quad(0,1)            | stage A0(o+2) -> buf1
        readB(bq1, Bb1, wn, 1, ln, quad);
        stageA(Xb, Ab1, m0, o + 2, 0, w, lane);
        BAR(); LGKM0();
        mfma16<0, 1>(acc, af, bq1);
        LGKM0(); BAR();
        // P7: quad(1,0)            | stage B0(o+2)
        readA(af, Ab1, wm, 1, ln, quad);
        stageB(Wt, Bb1, n0, o + 2, 0, w, lane);
        BAR(); LGKM0();
        mfma16<1, 0>(acc, af, bq0);
        LGKM0(); BAR();
        // P8: quad(1,1)            | stage B1(o+2) ; counted wait
        stageB(Wt, Bb1, n0, o + 2, 1, w, lane);
        BAR();
        mfma16<1, 1>(acc, af, bq1);
        VMC6(); BAR();
    }

    // ---- epilogue: tiles 14 (buf0), 15 (buf1); stage last unit then drain
    stageA(Xb, Ab1, m0, 15, 1, w, lane);
    VMC0(); BAR();

    readA(af, Ab0, wm, 0, ln, quad);
    readB(bq0, Bb0, wn, 0, ln, quad);
    readB(bq1, Bb0, wn, 1, ln, quad);
    mfma16<0, 0>(acc, af, bq0);
    mfma16<0, 1>(acc, af, bq1);
    readA(af, Ab0, wm, 1, ln, quad);
    mfma16<1, 0>(acc, af, bq0);
    mfma16<1, 1>(acc, af, bq1);

    readA(af, Ab1, wm, 0, ln, quad);
    readB(bq0, Bb1, wn, 0, ln, quad);
    readB(bq1, Bb1, wn, 1, ln, quad);
    mfma16<0, 0>(acc, af, bq0);
    mfma16<0, 1>(acc, af, bq1);
    readA(af, Ab1, wm, 1, ln, quad);
    mfma16<1, 0>(acc, af, bq0);
    mfma16<1, 1>(acc, af, bq1);

    // ---- C epilogue: n-tile selects Q / K / V^T (BN=256 divides 1024)
    const int which = n0 >> 10;
    float bv[4];
#pragma unroll
    for (int jj = 0; jj < 4; ++jj) bv[jj] = bias[n0 + wn * 64 + jj * 16 + ln];

    if (which < 2) {
        unsigned short* dst = (which == 0) ? Qp : Kp;
        const float qsc = (which == 0) ? 0.125f : 1.0f;   // fold 1/sqrt(hd) into Q
#pragma unroll
        for (int jj = 0; jj < 4; ++jj) {
            const int n = n0 + wn * 64 + jj * 16 + ln;
            const int h = (n >> 6) & 15, d = n & 63;
#pragma unroll
            for (int i = 0; i < 8; ++i)
#pragma unroll
                for (int r = 0; r < 4; ++r) {
                    const int m = m0 + wm * 128 + i * 16 + quad * 4 + r;
                    const int b = m >> 11, tt = m & 2047;
                    dst[(((size_t)(b * NHEAD + h) * T_SEQ) + tt) * HD + d] =
                        f2bf((acc[i][jj][r] + bv[jj]) * qsc);
                }
        }
    } else {
#pragma unroll
        for (int jj = 0; jj < 4; ++jj) {
            const int n = n0 + wn * 64 + jj * 16 + ln;
            const int c = n - 2048;                       // channel h*64+d
#pragma unroll
            for (int i = 0; i < 8; ++i) {
                const int m00 = m0 + wm * 128 + i * 16 + quad * 4;  // 4 consecutive tokens
                const int b = m00 >> 11, tt = m00 & 2047;
                ushort4 pk;
                pk.x = f2bf(acc[i][jj][0] + bv[jj]);
                pk.y = f2bf(acc[i][jj][1] + bv[jj]);
                pk.z = f2bf(acc[i][jj][2] + bv[jj]);
                pk.w = f2bf(acc[i][jj][3] + bv[jj]);
                *(ushort4*)&Vtp[(size_t)(b * 1024 + c) * T_SEQ + tt] = pk;
            }
        }
    }
}

// ---------------------------------------------------------------------------
// Kernel: proj GEMM -> fp32 out.  n-tiles on blockIdx.x (XCD L2).
// ---------------------------------------------------------------------------
__global__ __launch_bounds__(256) void proj_gemm(
    const unsigned short* __restrict__ Yin,   // [4096,1024] bf16
    const unsigned short* __restrict__ Wt,    // [1024,1024] bf16 (W^T)
    const float* __restrict__ bias,           // [1024]
    float* __restrict__ out)                  // [4096,1024] fp32
{
    __shared__ unsigned short As[128 * 64];
    __shared__ unsigned short Bs[128 * 64];
    const int m0 = blockIdx.y * 128;
    const int n0 = blockIdx.x * 128;

    f32x4 acc[4][4];
#pragma unroll
    for (int i = 0; i < 4; ++i)
#pragma unroll
        for (int j = 0; j < 4; ++j) acc[i][j] = (f32x4){0.f, 0.f, 0.f, 0.f};

    gemm128_core(Yin, Wt, CDIM, m0, n0, As, Bs, acc);

    const int tid = threadIdx.x;
    const int w = tid >> 6, lane = tid & 63;
    const int ln = lane & 15, quad = lane >> 4;
    const int wm = w >> 1, wn = w & 1;

#pragma unroll
    for (int j = 0; j < 4; ++j) {
        const int n = n0 + wn * 64 + j * 16 + ln;
        const float bv = bias[n];
#pragma unroll
        for (int i = 0; i < 4; ++i)
#pragma unroll
            for (int r = 0; r < 4; ++r) {
                const int m = m0 + wm * 64 + i * 16 + quad * 4 + r;
                out[(size_t)m * CDIM + n] = acc[i][j][r] + bv;
            }
    }
}

// ---------------------------------------------------------------------------
// Flash attention, R10-verified body, UNIFORM fine split-k:
//   qb 0-3  : unsplit  (chains <= 8 steps)          y = 40..43
//   qb 4-7  : 2-way    (chains <= 8 steps)          y = 32..39
//   qb 8-15 : 4-way    (chains <= 8 steps)          y =  0..31
//   grid (32 bh, 44) = 1408 blocks (5.5/CU -> backfill, no drain tail).
//   Segment s of an S-way split handles tiles j = s, s+S, ... (seg == j0).
//   Partials per bh: 8 (2-way) + 32 (4-way) = 40.  merge_attn combines.
//   R9 lesson kept: single-width steps, no loop-carried prefetch arrays.
// ---------------------------------------------------------------------------

// ushort index in a [64][64] bf16 tile; slot = 16B-chunk 0..7, XOR-swizzled
__device__ __forceinline__ int swz(int row, int slot) {
    return row * 64 + ((slot ^ (row & 7)) << 3);
}

__global__ __launch_bounds__(256) void flash_attn32(
    const unsigned short* __restrict__ Qp,   // [BH, T, 64]  (Q pre-scaled 0.125)
    const unsigned short* __restrict__ Kp,   // [BH, T, 64]
    const unsigned short* __restrict__ Vtp,  // [BH, 64, T]
    const int* __restrict__ mask,            // [B, T]
    unsigned short* __restrict__ Y,          // [B*T, 1024] bf16
    unsigned short* __restrict__ Po,         // [32*40, 128, 64] bf16 partial O
    float* __restrict__ Pm,                  // [32*40, 128] partial m
    float* __restrict__ Pl)                  // [32*40, 128] partial l
{
    __shared__ unsigned short Ks[64 * 64];   // swizzled
    __shared__ unsigned short Vs[64 * 64];   // swizzled (V^T: rows=d)
    __shared__ float mask_arr[64];           // permuted to reg order
    __shared__ float als[4][32];             // per-warp alpha / 1/l broadcast
    __shared__ int flagu;                    // 0 = all 64 tokens valid this tile

    const int bh = blockIdx.x;
    const int y = blockIdx.y;
    int qb, j0, jstep;
    bool split;
    if (y < 32)      { qb = 15 - (y >> 2);        j0 = y & 3;        jstep = 4; split = true; }
    else if (y < 40) { qb = 7 - ((y - 32) >> 1);  j0 = (y - 32) & 1; jstep = 2; split = true; }
    else             { qb = 43 - y;               j0 = 0;            jstep = 1; split = false; }
    // partial index: 2-way at local 0..7, 4-way at local 8..39 (seg == j0)
    const int pidx = split
        ? ((qb < 8) ? (bh * 40 + (qb - 4) * 2 + j0)
                    : (bh * 40 + 8 + (qb - 8) * 4 + j0))
        : 0;

    const int b = bh >> 4, h = bh & 15;
    const int tid = threadIdx.x;
    const int w = tid >> 6, lane = tid & 63;
    const int l31 = lane & 31, hi = lane >> 5;
    const int row8 = tid >> 3, seg = tid & 7;
    const size_t base = (size_t)bh * T_SEQ * HD;
    const int qB = qb * 128;
    const int qw0 = qB + w * 32;
    const int qv = qw0 + l31;                // this lane's softmax q-row
    const int jlast = 2 * qb + 1;

    // Q fragments: qf[c] = Q[qv][c*16 + hi*8 .. +8]  (B-operand of swapped QK^T)
    U16x8 qf[4];
    {
        const unsigned short* qrow = &Qp[base + (size_t)qv * HD];
#pragma unroll
        for (int c = 0; c < 4; ++c)
            qf[c].u4 = *(const uint4*)&qrow[c * 16 + hi * 8];
    }

    f32x16 oA0, oA1;
#pragma unroll
    for (int r = 0; r < 16; ++r) { oA0[r] = 0.f; oA1[r] = 0.f; }
    float m_r = -3.0e38f, mL = 0.f, l_r = 0.f;

    // register prefetch of tile j0
    uint4 kr0, kr1, vr0, vr1;
    float mf = 0.f;
    {
        const unsigned short* kp0 = &Kp[base + (size_t)(j0 * 64 + row8) * HD + seg * 8];
        kr0 = *(const uint4*)kp0;
        kr1 = *(const uint4*)(kp0 + 32 * HD);
        const unsigned short* vp0 = &Vtp[base + (size_t)row8 * T_SEQ + j0 * 64 + seg * 8];
        vr0 = *(const uint4*)vp0;
        vr1 = *(const uint4*)(vp0 + 32 * T_SEQ);
        if (tid < 64) mf = mask[b * T_SEQ + j0 * 64 + tid] ? 0.f : -1.0e30f;
    }

    for (int j = j0; j <= jlast; j += jstep) {
        __syncthreads();
        *(uint4*)&Ks[swz(row8, seg)]      = kr0;
        *(uint4*)&Ks[swz(row8 + 32, seg)] = kr1;
        *(uint4*)&Vs[swz(row8, seg)]      = vr0;
        *(uint4*)&Vs[swz(row8 + 32, seg)] = vr1;
        if (w == 0) {
            // mask value for token k=lane -> reg-order slot (hi,kb,g,k&3)
            const int k = lane;
            const int idx = ((k >> 2) & 1) * 32 + (k >> 5) * 16 + ((k & 31) >> 3) * 4 + (k & 3);
            mask_arr[idx] = mf;
            const unsigned long long bb = __ballot(mf == 0.f);
            if (lane == 0) flagu = (bb == 0xFFFFFFFFFFFFFFFFull) ? 0 : 1;
        }
        __syncthreads();

        const int jn = j + jstep;
        if (jn <= jlast) {   // prefetch next tile of this segment
            const unsigned short* kp0 = &Kp[base + (size_t)(jn * 64 + row8) * HD + seg * 8];
            kr0 = *(const uint4*)kp0;
            kr1 = *(const uint4*)(kp0 + 32 * HD);
            const unsigned short* vp0 = &Vtp[base + (size_t)row8 * T_SEQ + jn * 64 + seg * 8];
            vr0 = *(const uint4*)vp0;
            vr1 = *(const uint4*)(vp0 + 32 * T_SEQ);
            if (tid < 64) mf = mask[b * T_SEQ + jn * 64 + tid] ? 0.f : -1.0e30f;
        }

        const bool skipw = (j * 64 > qw0 + 31);
        if (!skipw) {
            const bool edge = (j * 64 + 63 > qw0);
            const int anymask = flagu;

            // ---- S^T = K Q^T  (two 32-k halves; Q pre-scaled)
            f32x16 sc0, sc1;
#pragma unroll
            for (int r = 0; r < 16; ++r) { sc0[r] = 0.f; sc1[r] = 0.f; }
#pragma unroll
            for (int c = 0; c < 4; ++c) {
                U16x8 ka0, ka1;
                const int r0 = l31, r1 = 32 + l31;
                ka0.u4 = *(const uint4*)&Ks[r0 * 64 + (((2 * c + hi) ^ (r0 & 7)) << 3)];
                ka1.u4 = *(const uint4*)&Ks[r1 * 64 + (((2 * c + hi) ^ (r1 & 7)) << 3)];
                sc0 = __builtin_amdgcn_mfma_f32_32x32x16_bf16(ka0.b, qf[c].b, sc0, 0, 0, 0);
                sc1 = __builtin_amdgcn_mfma_f32_32x32x16_bf16(ka1.b, qf[c].b, sc1, 0, 0, 0);
            }

            // ---- pad mask (pure add; scale already folded into Q)
            if (anymask) {
#pragma unroll
                for (int g = 0; g < 4; ++g) {
                    const f32x4 m0v = *(const f32x4*)&mask_arr[hi * 32 + g * 4];
                    const f32x4 m1v = *(const f32x4*)&mask_arr[hi * 32 + 16 + g * 4];
#pragma unroll
                    for (int t = 0; t < 4; ++t) {
                        sc0[g * 4 + t] += m0v[t];
                        sc1[g * 4 + t] += m1v[t];
                    }
                }
            }
            // ---- causal edge: k_global > q -> -inf
            if (edge) {
#pragma unroll
                for (int r = 0; r < 16; ++r) {
                    const int krow = (r & 3) + 8 * (r >> 2) + 4 * hi;
                    if (j * 64 + krow > qv)      sc0[r] = -1.0e30f;
                    if (j * 64 + 32 + krow > qv) sc1[r] = -1.0e30f;
                }
            }

            // ---- tile max (in-lane 32 values, then lane<->lane+32 merge)
            float tm = -3.0e38f;
#pragma unroll
            for (int r = 0; r < 16; ++r)
                tm = fmaxf(tm, fmaxf(sc0[r], sc1[r]));
            tm = fmaxf(tm, __shfl_xor(tm, 32));

            // ---- defer-max: rescale only if max grew > THR
            if (__any(tm > m_r + 8.f)) {
                const float mn = fmaxf(m_r, tm);
                const float a = __builtin_amdgcn_exp2f((m_r - mn) * LOG2E);
                m_r = mn; mL = mn * LOG2E;
                l_r *= a;
                if (hi == 0) als[w][l31] = a;      // alpha indexed by q
                f32x4 av[4];
#pragma unroll
                for (int g = 0; g < 4; ++g)
                    av[g] = *(const f32x4*)&als[w][g * 8 + hi * 4];
#pragma unroll
                for (int r = 0; r < 16; ++r) {
                    const float aa = av[r >> 2][r & 3];
                    oA0[r] *= aa; oA1[r] *= aa;
                }
            }

            // ---- exp + per-lane partial sum
            float ps = 0.f;
#pragma unroll
            for (int r = 0; r < 16; ++r) {
                const float p0 = __builtin_amdgcn_exp2f(fmaf(sc0[r], LOG2E, -mL));
                const float p1 = __builtin_amdgcn_exp2f(fmaf(sc1[r], LOG2E, -mL));
                sc0[r] = p0; sc1[r] = p1;
                ps += p0 + p1;
            }
            l_r += ps;

            // ---- P -> bf16 A-frags (cvt_pk + permlane32_swap) ; O += P V
#pragma unroll
            for (int c = 0; c < 4; ++c) {
                const int rb = (c & 1) * 8;
                unsigned int x0, y0, x1, y1;
                if (c < 2) {
                    x0 = cvtpk_bf16(sc0[rb + 0], sc0[rb + 1]);
                    y0 = cvtpk_bf16(sc0[rb + 4], sc0[rb + 5]);
                    x1 = cvtpk_bf16(sc0[rb + 2], sc0[rb + 3]);
                    y1 = cvtpk_bf16(sc0[rb + 6], sc0[rb + 7]);
                } else {
                    x0 = cvtpk_bf16(sc1[rb + 0], sc1[rb + 1]);
                    y0 = cvtpk_bf16(sc1[rb + 4], sc1[rb + 5]);
                    x1 = cvtpk_bf16(sc1[rb + 2], sc1[rb + 3]);
                    y1 = cvtpk_bf16(sc1[rb + 6], sc1[rb + 7]);
                }
                plane32swap(x0, y0);   // x0 -> au[0] (j=0,1), y0 -> au[2] (j=4,5)
                plane32swap(x1, y1);   // x1 -> au[1] (j=2,3), y1 -> au[3] (j=6,7)
                U16x8 pa;
                pa.u4 = make_uint4(x0, x1, y0, y1);
                {
                    const int vr_0 = l31, vr_1 = 32 + l31;
                    U16x8 vb0, vb1;
                    vb0.u4 = *(const uint4*)&Vs[vr_0 * 64 + (((2 * c + hi) ^ (vr_0 & 7)) << 3)];
                    vb1.u4 = *(const uint4*)&Vs[vr_1 * 64 + (((2 * c + hi) ^ (vr_1 & 7)) << 3)];
                    oA0 = __builtin_amdgcn_mfma_f32_32x32x16_bf16(pa.b, vb0.b, oA0, 0, 0, 0);
                    oA1 = __builtin_amdgcn_mfma_f32_32x32x16_bf16(pa.b, vb1.b, oA1, 0, 0, 0);
                }
            }
        }
    }

    // ---- hi-merge of the row-sum partial (each lane covers its hi-half)
    const float lt = l_r + __shfl_xor(l_r, 32);

    if (split) {
        // ---- write unnormalized partials (O-layout rows, lane-q m/l)
        if (hi == 0) {
            Pm[pidx * 128 + w * 32 + l31] = m_r;
            Pl[pidx * 128 + w * 32 + l31] = lt;
        }
#pragma unroll
        for (int r = 0; r < 16; ++r) {
            const int qlc = w * 32 + (r & 3) + 8 * (r >> 2) + 4 * hi;
            Po[(size_t)pidx * 8192 + qlc * 64 + l31]      = f2bf(oA0[r]);
            Po[(size_t)pidx * 8192 + qlc * 64 + 32 + l31] = f2bf(oA1[r]);
        }
    } else {
        // ---- normalize + store
        if (hi == 0) als[w][l31] = 1.0f / lt;
        f32x4 lv[4];
#pragma unroll
        for (int g = 0; g < 4; ++g)
            lv[g] = *(const f32x4*)&als[w][g * 8 + hi * 4];
#pragma unroll
        for (int r = 0; r < 16; ++r) {
            const int q = qw0 + (r & 3) + 8 * (r >> 2) + 4 * hi;
            const float sl = lv[r >> 2][r & 3];
            const size_t row = (size_t)(b * T_SEQ + q);
            Y[row * CDIM + h * HD + l31]      = f2bf(oA0[r] * sl);
            Y[row * CDIM + h * HD + 32 + l31] = f2bf(oA1[r] * sl);
        }
    }
}

// ---------------------------------------------------------------------------
// Merge the S segments of each split (bh, qb in 4..15) chunk.
//   O = (sum_s f_s*O_s) / (sum_s f_s*l_s),  f_s = exp(m_s - max_s m_s).
//   S = 2 for qb 4..7, S = 4 for qb 8..15.
//   grid 1536 = 32 bh x 12 qb x 4 parts; thread -> (q row, 8 d cols).
// ---------------------------------------------------------------------------
__global__ __launch_bounds__(256) void merge_attn(
    const unsigned short* __restrict__ Po,
    const float* __restrict__ Pm, const float* __restrict__ Pl,
    unsigned short* __restrict__ Y)
{
    const int u = blockIdx.x;
    const int bh = u & 31;
    const int v = u >> 5;                 // 0..47
    const int qb = 4 + (v >> 2), part = v & 3;
    const int tid = threadIdx.x;
    const int ql = part * 32 + (tid >> 3);
    const int d0 = (tid & 7) * 8;
    const int b = bh >> 4, h = bh & 15;

    int S, basei;
    if (qb < 8) { S = 2; basei = bh * 40 + (qb - 4) * 2; }
    else        { S = 4; basei = bh * 40 + 8 + (qb - 8) * 4; }

    float mv[4], lv[4];
    float M = -3.0e38f;
#pragma unroll
    for (int s = 0; s < 4; ++s) {
        if (s < S) {
            mv[s] = Pm[(basei + s) * 128 + ql];
            lv[s] = Pl[(basei + s) * 128 + ql];
            M = fmaxf(M, mv[s]);
        }
    }
    float f[4], L = 0.f;
#pragma unroll
    for (int s = 0; s < 4; ++s) {
        if (s < S) {
            f[s] = __builtin_amdgcn_exp2f((mv[s] - M) * LOG2E);
            L += f[s] * lv[s];
        }
    }
    const float inv = 1.0f / L;

    float o[8] = {0.f, 0.f, 0.f, 0.f, 0.f, 0.f, 0.f, 0.f};
#pragma unroll
    for (int s = 0; s < 4; ++s) {
        if (s < S) {
            U16x8 a;
            a.u4 = *(const uint4*)&Po[(size_t)(basei + s) * 8192 + ql * 64 + d0];
#pragma unroll
            for (int j = 0; j < 8; ++j) o[j] += f[s] * bf2f(a.s[j]);
        }
    }

    U16x8 ot;
#pragma unroll
    for (int j = 0; j < 8; ++j) ot.s[j] = f2bf(o[j] * inv);

    const int q = qb * 128 + ql;
    *(uint4*)&Y[(size_t)(b * T_SEQ + q) * CDIM + h * HD + d0] = ot.u4;
}

// ---------------------------------------------------------------------------
extern "C" void kernel_launch(void* const* d_in, const int* in_sizes, int n_in,
                              void* d_out, int out_size, void* d_ws, size_t ws_size,
                              hipStream_t stream)
{
    const float* X     = (const float*)d_in[0];
    const int*   mask  = (const int*)d_in[1];
    const float* Wqkv  = (const float*)d_in[2];
    const float* bqkv  = (const float*)d_in[3];
    const float* Wproj = (const float*)d_in[4];
    const float* bproj = (const float*)d_in[5];
    float* out = (float*)d_out;

    const size_t per = (size_t)2 * NHEAD * T_SEQ * HD;   // 4,194,304 elems
    unsigned short* Qp     = (unsigned short*)d_ws;
    unsigned short* Kp     = Qp + per;
    unsigned short* Vtp    = Kp + per;
    unsigned short* Xb     = Vtp + per;                  // aliased: Yp reuses Xb
    unsigned short* Yp     = Xb;                         // X consumed before Y written
    unsigned short* Wprojt = Xb + per;                   // [1024,1024]
    unsigned short* Wqkvt  = Wprojt + (size_t)CDIM * CDIM;     // [3072,1024]
    // Po aliases Wqkvt (dead after qkv8; stream-ordered) and extends past it
    unsigned short* Po     = Wqkvt;                      // [1280,128,64] bf16
    float*          Pm     = (float*)(Po + (size_t)1280 * 8192);
    float*          Pl     = Pm + 1280 * 128;

    prep<<<3072, 256, 0, stream>>>(X, Xb, Wqkv, Wqkvt, Wproj, Wprojt);
    qkv8<<<192, 512, 0, stream>>>(Xb, Wqkvt, bqkv, Qp, Kp, Vtp);
    flash_attn32<<<dim3(2 * NHEAD, 44), 256, 0, stream>>>(Qp, Kp, Vtp, mask, Yp, Po, Pm, Pl);
    merge_attn<<<1536, 256, 0, stream>>>(Po, Pm, Pl, Yp);
    proj_gemm<<<dim3(8, 32), 256, 0, stream>>>(Yp, Wprojt, bproj, out);
}

// Round 12
// 206.704 us; speedup vs baseline: 1.1244x; 1.0133x over previous
//
#include <hip/hip_runtime.h>

#define T_SEQ 2048
#define NHEAD 16
#define HD 64
#define CDIM 1024

typedef __bf16 bf16x8 __attribute__((ext_vector_type(8)));
typedef float f32x4 __attribute__((ext_vector_type(4)));
typedef float f32x16 __attribute__((ext_vector_type(16)));

union U16x8 { uint4 u4; unsigned short s[8]; bf16x8 b; };

__device__ __forceinline__ float bf2f(unsigned short u) {
    return __uint_as_float(((unsigned int)u) << 16);
}
__device__ __forceinline__ unsigned short f2bf(float f) {
    unsigned int u = __float_as_uint(f);
    u += 0x7fffu + ((u >> 16) & 1u);   // round-to-nearest-even
    return (unsigned short)(u >> 16);
}
__device__ __forceinline__ U16x8 load8f(const float* __restrict__ p) {
    U16x8 r;
    float4 f0 = *(const float4*)p;
    float4 f1 = *(const float4*)(p + 4);
    r.s[0] = f2bf(f0.x); r.s[1] = f2bf(f0.y); r.s[2] = f2bf(f0.z); r.s[3] = f2bf(f0.w);
    r.s[4] = f2bf(f1.x); r.s[5] = f2bf(f1.y); r.s[6] = f2bf(f1.z); r.s[7] = f2bf(f1.w);
    return r;
}

// async global->LDS, 16 B per lane; LDS dest = wave-uniform base + lane*16
__device__ __forceinline__ void async_copy16(const unsigned short* g, unsigned short* l) {
    __builtin_amdgcn_global_load_lds(
        (const __attribute__((address_space(1))) unsigned int*)g,
        (__attribute__((address_space(3))) unsigned int*)l, 16, 0, 0);
}

#define LOG2E 1.442695040f

// raw barrier / counted waits (NEVER __syncthreads in the 8-phase loop: it drains vmcnt)
#define BAR()    asm volatile("s_barrier" ::: "memory")
#define LGKM0()  asm volatile("s_waitcnt lgkmcnt(0)" ::: "memory")
#define VMC6()   asm volatile("s_waitcnt vmcnt(6)" ::: "memory")
#define VMC0()   asm volatile("s_waitcnt vmcnt(0)" ::: "memory")

// v_cvt_pk_bf16_f32: D.lo = bf16(lo), D.hi = bf16(hi)
__device__ __forceinline__ unsigned int cvtpk_bf16(float lo, float hi) {
    unsigned int r;
    asm("v_cvt_pk_bf16_f32 %0, %1, %2" : "=v"(r) : "v"(lo), "v"(hi));
    return r;
}
// x' = {x[0:31], y[0:31]}, y' = {x[32:63], y[32:63]}
__device__ __forceinline__ void plane32swap(unsigned int &x, unsigned int &y) {
    asm("v_permlane32_swap_b32 %0, %1" : "+v"(x), "+v"(y));
}

// ---------------------------------------------------------------------------
// Merged prep kernel (R7-verified): conv + both weight transposes.
// ---------------------------------------------------------------------------
__device__ __forceinline__ void transpose_tile(
    const float* __restrict__ in, unsigned short* __restrict__ out,
    int R, int C, int r0, int c0, float tile[64][65])
{
    const int tid = threadIdx.x;
    const int rr = tid >> 4;
    const int cc = (tid & 15) * 4;
#pragma unroll
    for (int p = 0; p < 4; ++p) {
        float4 v = *(const float4*)&in[(size_t)(r0 + p * 16 + rr) * C + c0 + cc];
        tile[p * 16 + rr][cc] = v.x;
        tile[p * 16 + rr][cc + 1] = v.y;
        tile[p * 16 + rr][cc + 2] = v.z;
        tile[p * 16 + rr][cc + 3] = v.w;
    }
    __syncthreads();
    const int n = tid >> 2;
    const int s = (tid & 3) * 8;
#pragma unroll
    for (int p = 0; p < 2; ++p) {
        const int k = s + p * 32;
        U16x8 o;
#pragma unroll
        for (int j = 0; j < 8; ++j) o.s[j] = f2bf(tile[k + j][n]);
        *(uint4*)&out[(size_t)(c0 + n) * R + r0 + k] = o.u4;
    }
}

__global__ __launch_bounds__(256) void prep(
    const float* __restrict__ X,     unsigned short* __restrict__ Xb,
    const float* __restrict__ Wqkv,  unsigned short* __restrict__ Wqkvt,
    const float* __restrict__ Wproj, unsigned short* __restrict__ Wprojt)
{
    __shared__ float tile[64][65];
    const int bid = blockIdx.x;
    if (bid < 2048) {
        const int i = (bid * 256 + threadIdx.x) * 8;
        U16x8 o = load8f(&X[i]);
        *(uint4*)&Xb[i] = o.u4;
    } else if (bid < 2816) {
        const int u = bid - 2048;
        transpose_tile(Wqkv, Wqkvt, CDIM, 3 * CDIM, (u & 15) * 64, (u >> 4) * 64, tile);
    } else {
        const int u = bid - 2816;
        transpose_tile(Wproj, Wprojt, CDIM, CDIM, (u & 15) * 64, (u >> 4) * 64, tile);
    }
}

// ---------------------------------------------------------------------------
// m97-style GEMM core (kept for proj): C[128x128] = A[M,K] * Bt[N,K]^T
// ---------------------------------------------------------------------------
__device__ __forceinline__ void gemm128_core(
    const unsigned short* __restrict__ A,
    const unsigned short* __restrict__ Bt,
    int K, int m0, int n0,
    unsigned short* As, unsigned short* Bs, f32x4 acc[4][4])
{
    const int tid = threadIdx.x;
    const int w = tid >> 6, lane = tid & 63;
    const int ln = lane & 15, quad = lane >> 4;
    const int wm = w >> 1, wn = w & 1;
    const int lr = lane >> 3;        // 0..7
    const int lc = (lane & 7) * 8;   // col start (elems)

    for (int kb = 0; kb < K; kb += 64) {
        __syncthreads();
#pragma unroll
        for (int i = 0; i < 4; ++i) {
            async_copy16(&A[(size_t)(m0 + w * 32 + i * 8 + lr) * K + kb + lc],
                         &As[(w * 32 + i * 8) * 64]);
            async_copy16(&Bt[(size_t)(n0 + w * 32 + i * 8 + lr) * K + kb + lc],
                         &Bs[(w * 32 + i * 8) * 64]);
        }
        __syncthreads();
#pragma unroll
        for (int kk = 0; kk < 2; ++kk) {
            U16x8 af[4], bff[4];
#pragma unroll
            for (int i = 0; i < 4; ++i)
                af[i].u4 = *(const uint4*)&As[(wm * 64 + i * 16 + ln) * 64 + kk * 32 + quad * 8];
#pragma unroll
            for (int j = 0; j < 4; ++j)
                bff[j].u4 = *(const uint4*)&Bs[(wn * 64 + j * 16 + ln) * 64 + kk * 32 + quad * 8];
#pragma unroll
            for (int i = 0; i < 4; ++i)
#pragma unroll
                for (int j = 0; j < 4; ++j)
                    acc[i][j] = __builtin_amdgcn_mfma_f32_16x16x32_bf16(af[i].b, bff[j].b, acc[i][j], 0, 0, 0);
        }
    }
}

// ---------------------------------------------------------------------------
// 256x256 8-phase counted-vmcnt GEMM (T2+T3+T4+T5), fused QKV epilogue.
// Q slice pre-scaled by 0.125 (folds 1/sqrt(hd) out of flash; R9-verified).
// ---------------------------------------------------------------------------
__device__ __forceinline__ void stageA(const unsigned short* __restrict__ A,
                                       unsigned short* buf,
                                       int m0, int t, int unit, int w, int lane)
{
#pragma unroll
    for (int s = 0; s < 2; ++s) {
        const int r0 = s * 128 + unit * 64 + w * 8;          // wave-uniform
        const int row = r0 + (lane >> 3);
        const int col = (16 * (lane & 7)) ^ ((row & 4) ? 32 : 0);  // bytes, pre-swizzled src
        const unsigned short* src = A + (size_t)(m0 + row) * CDIM + t * 64 + (col >> 1);
        async_copy16(src, buf + r0 * 64);                    // linear LDS dest
    }
}

__device__ __forceinline__ void stageB(const unsigned short* __restrict__ B,
                                       unsigned short* buf,
                                       int n0, int t, int unit, int w, int lane)
{
#pragma unroll
    for (int s = 0; s < 2; ++s) {
        const int slice = s * 8 + w;
        const int r0 = (slice >> 2) * 64 + unit * 32 + (slice & 3) * 8;  // wave-uniform
        const int row = r0 + (lane >> 3);
        const int col = (16 * (lane & 7)) ^ ((row & 4) ? 32 : 0);
        const unsigned short* src = B + (size_t)(n0 + row) * CDIM + t * 64 + (col >> 1);
        async_copy16(src, buf + r0 * 64);
    }
}

__device__ __forceinline__ void readA(U16x8 af[4][2], const unsigned short* buf,
                                      int wm, int qm, int ln, int quad)
{
#pragma unroll
    for (int i = 0; i < 4; ++i) {
        const int row = wm * 128 + qm * 64 + i * 16 + ln;
        const int sw = (row & 4) ? 32 : 0;
#pragma unroll
        for (int kk = 0; kk < 2; ++kk) {
            const int byt = row * 128 + ((kk * 64 + quad * 16) ^ sw);
            af[i][kk].u4 = *(const uint4*)((const char*)buf + byt);
        }
    }
}

__device__ __forceinline__ void readB(U16x8 bf[2][2], const unsigned short* buf,
                                      int wn, int qn, int ln, int quad)
{
#pragma unroll
    for (int jj = 0; jj < 2; ++jj) {
        const int row = wn * 64 + qn * 32 + jj * 16 + ln;
        const int sw = (row & 4) ? 32 : 0;
#pragma unroll
        for (int kk = 0; kk < 2; ++kk) {
            const int byt = row * 128 + ((kk * 64 + quad * 16) ^ sw);
            bf[jj][kk].u4 = *(const uint4*)((const char*)buf + byt);
        }
    }
}

template<int QM, int QN>
__device__ __forceinline__ void mfma16(f32x4 acc[8][4], const U16x8 af[4][2],
                                       const U16x8 bf[2][2])
{
    __builtin_amdgcn_s_setprio(1);
#pragma unroll
    for (int i = 0; i < 4; ++i)
#pragma unroll
        for (int jj = 0; jj < 2; ++jj)
#pragma unroll
            for (int kk = 0; kk < 2; ++kk)
                acc[QM * 4 + i][QN * 2 + jj] = __builtin_amdgcn_mfma_f32_16x16x32_bf16(
                    af[i][kk].b, bf[jj][kk].b, acc[QM * 4 + i][QN * 2 + jj], 0, 0, 0);
    __builtin_amdgcn_s_setprio(0);
}

__global__ __launch_bounds__(512) void qkv8(
    const unsigned short* __restrict__ Xb,    // [4096,1024] bf16
    const unsigned short* __restrict__ Wt,    // [3072,1024] bf16 (W^T; V rows at 2048)
    const float* __restrict__ bias,           // [3072]
    unsigned short* __restrict__ Qp,
    unsigned short* __restrict__ Kp,
    unsigned short* __restrict__ Vtp)         // [B,1024,T]
{
    __shared__ __align__(1024) unsigned short smem[4][16384];  // Abuf0,Abuf1,Bbuf0,Bbuf1
    unsigned short* Ab0 = smem[0];
    unsigned short* Ab1 = smem[1];
    unsigned short* Bb0 = smem[2];
    unsigned short* Bb1 = smem[3];

    const int tid = threadIdx.x;
    const int w = tid >> 6, lane = tid & 63;
    const int ln = lane & 15, quad = lane >> 4;
    const int wm = w >> 2, wn = w & 3;

    // bijective XCD swizzle (192 % 8 == 0): 24 consecutive tiles per XCD
    const int bid = blockIdx.x;
    const int swz = (bid & 7) * 24 + (bid >> 3);
    const int nt = swz % 12, mt = swz / 12;
    const int m0 = mt * 256, n0 = nt * 256;

    f32x4 acc[8][4];
#pragma unroll
    for (int i = 0; i < 8; ++i)
#pragma unroll
        for (int j = 0; j < 4; ++j) acc[i][j] = (f32x4){0.f, 0.f, 0.f, 0.f};

    // ---- prologue: 7 units (tile 0 complete + tile 1 A0/B0/B1), depth-3 pipe
    stageA(Xb, Ab0, m0, 0, 0, w, lane);
    stageB(Wt, Bb0, n0, 0, 0, w, lane);
    stageB(Wt, Bb0, n0, 0, 1, w, lane);
    stageA(Xb, Ab0, m0, 0, 1, w, lane);
    stageA(Xb, Ab1, m0, 1, 0, w, lane);
    stageB(Wt, Bb1, n0, 1, 0, w, lane);
    stageB(Wt, Bb1, n0, 1, 1, w, lane);
    VMC6();            // oldest 4 units (= tile 0) landed
    BAR();

    U16x8 af[4][2], bq0[2][2], bq1[2][2];

    // ---- main loop: 7 iters x 2 K-tiles; tiles 0..13
    for (int j = 0; j < 7; ++j) {
        const int e = 2 * j, o = 2 * j + 1;
        // P1: quad(0,0) of tile e  | stage A1(o) -> buf1
        readA(af, Ab0, wm, 0, ln, quad);
        readB(bq0, Bb0, wn, 0, ln, quad);
        stageA(Xb, Ab1, m0, o, 1, w, lane);
        BAR(); LGKM0();
        mfma16<0, 0>(acc, af, bq0);
        LGKM0(); BAR();
        // P2: quad(0,1)            | stage A0(e+2) -> buf0
        readB(bq1, Bb0, wn, 1, ln, quad);
        stageA(Xb, Ab0, m0, e + 2, 0, w, lane);
        BAR(); LGKM0();
        mfma16<0, 1>(acc, af, bq1);
        LGKM0(); BAR();
        // P3: quad(1,0)            | stage B0(e+2)
        readA(af, Ab0, wm, 1, ln, quad);
        stageB(Wt, Bb0, n0, e + 2, 0, w, lane);
        BAR(); LGKM0();
        mfma16<1, 0>(acc, af, bq0);
        LGKM0(); BAR();
        // P4: quad(1,1)            | stage B1(e+2) ; counted wait
        stageB(Wt, Bb0, n0, e + 2, 1, w, lane);
        BAR();
        mfma16<1, 1>(acc, af, bq1);
        VMC6(); BAR();
        // P5: quad(0,0) of tile o  | stage A1(e+2) -> buf0
        readA(af, Ab1, wm, 0, ln, quad);
        readB(bq0, Bb1, wn, 0, ln, quad);
        stageA(Xb, Ab0, m0, e + 2, 1, w, lane);
        BAR(); LGKM0();
        mfma16<0, 0>(acc, af, bq0);
        LGKM0(); BAR();
        // P6: quad(0,1)            | stage A0(o+2) -> buf1
        readB(bq1, Bb1, wn, 1, ln, quad);
        stageA(Xb, Ab1, m0, o + 2, 0, w, lane);
        BAR(); LGKM0();
        mfma16<0, 1>(acc, af, bq1);
        LGKM0(); BAR();
        // P7: quad(1,0)            | stage B0(o+2)
        readA(af, Ab1, wm, 1, ln, quad);
        stageB(Wt, Bb1, n0, o + 2, 0, w, lane);
        BAR(); LGKM0();
        mfma16<1, 0>(acc, af, bq0);
        LGKM0(); BAR();
        // P8: quad(1,1)            | stage B1(o+2) ; counted wait
        stageB(Wt, Bb1, n0, o + 2, 1, w, lane);
        BAR();
        mfma16<1, 1>(acc, af, bq1);
        VMC6(); BAR();
    }

    // ---- epilogue: tiles 14 (buf0), 15 (buf1); stage last unit then drain
    stageA(Xb, Ab1, m0, 15, 1, w, lane);
    VMC0(); BAR();

    readA(af, Ab0, wm, 0, ln, quad);
    readB(bq0, Bb0, wn, 0, ln, quad);
    readB(bq1, Bb0, wn, 1, ln, quad);
    mfma16<0, 0>(acc, af, bq0);
    mfma16<0, 1>(acc, af, bq1);
    readA(af, Ab0, wm, 1, ln, quad);
    mfma16<1, 0>(acc, af, bq0);
    mfma16<1, 1>(acc, af, bq1);

    readA(af, Ab1, wm, 0, ln, quad);
    readB(bq0, Bb1, wn, 0, ln, quad);
    readB(bq1, Bb1, wn, 1, ln, quad);
    mfma16<0, 0>(acc, af, bq0);
    mfma16<0, 1>(acc, af, bq1);
    readA(af, Ab1, wm, 1, ln, quad);
    mfma16<1, 0>(acc, af, bq0);
    mfma16<1, 1>(acc, af, bq1);

    // ---- C epilogue: n-tile selects Q / K / V^T (BN=256 divides 1024)
    const int which = n0 >> 10;
    float bv[4];
#pragma unroll
    for (int jj = 0; jj < 4; ++jj) bv[jj] = bias[n0 + wn * 64 + jj * 16 + ln];

    if (which < 2) {
        unsigned short* dst = (which == 0) ? Qp : Kp;
        const float qsc = (which == 0) ? 0.125f : 1.0f;   // fold 1/sqrt(hd) into Q
#pragma unroll
        for (int jj = 0; jj < 4; ++jj) {
            const int n = n0 + wn * 64 + jj * 16 + ln;
            const int h = (n >> 6) & 15, d = n & 63;
#pragma unroll
            for (int i = 0; i < 8; ++i)
#pragma unroll
                for (int r = 0; r < 4; ++r) {
                    const int m = m0 + wm * 128 + i * 16 + quad * 4 + r;
                    const int b = m >> 11, tt = m & 2047;
                    dst[(((size_t)(b * NHEAD + h) * T_SEQ) + tt) * HD + d] =
                        f2bf((acc[i][jj][r] + bv[jj]) * qsc);
                }
        }
    } else {
#pragma unroll
        for (int jj = 0; jj < 4; ++jj) {
            const int n = n0 + wn * 64 + jj * 16 + ln;
            const int c = n - 2048;                       // channel h*64+d
#pragma unroll
            for (int i = 0; i < 8; ++i) {
                const int m00 = m0 + wm * 128 + i * 16 + quad * 4;  // 4 consecutive tokens
                const int b = m00 >> 11, tt = m00 & 2047;
                ushort4 pk;
                pk.x = f2bf(acc[i][jj][0] + bv[jj]);
                pk.y = f2bf(acc[i][jj][1] + bv[jj]);
                pk.z = f2bf(acc[i][jj][2] + bv[jj]);
                pk.w = f2bf(acc[i][jj][3] + bv[jj]);
                *(ushort4*)&Vtp[(size_t)(b * 1024 + c) * T_SEQ + tt] = pk;
            }
        }
    }
}

// ---------------------------------------------------------------------------
// Kernel: proj GEMM -> fp32 out.  n-tiles on blockIdx.x (XCD L2).
// ---------------------------------------------------------------------------
__global__ __launch_bounds__(256) void proj_gemm(
    const unsigned short* __restrict__ Yin,   // [4096,1024] bf16
    const unsigned short* __restrict__ Wt,    // [1024,1024] bf16 (W^T)
    const float* __restrict__ bias,           // [1024]
    float* __restrict__ out)                  // [4096,1024] fp32
{
    __shared__ unsigned short As[128 * 64];
    __shared__ unsigned short Bs[128 * 64];
    const int m0 = blockIdx.y * 128;
    const int n0 = blockIdx.x * 128;

    f32x4 acc[4][4];
#pragma unroll
    for (int i = 0; i < 4; ++i)
#pragma unroll
        for (int j = 0; j < 4; ++j) acc[i][j] = (f32x4){0.f, 0.f, 0.f, 0.f};

    gemm128_core(Yin, Wt, CDIM, m0, n0, As, Bs, acc);

    const int tid = threadIdx.x;
    const int w = tid >> 6, lane = tid & 63;
    const int ln = lane & 15, quad = lane >> 4;
    const int wm = w >> 1, wn = w & 1;

#pragma unroll
    for (int j = 0; j < 4; ++j) {
        const int n = n0 + wn * 64 + j * 16 + ln;
        const float bv = bias[n];
#pragma unroll
        for (int i = 0; i < 4; ++i)
#pragma unroll
            for (int r = 0; r < 4; ++r) {
                const int m = m0 + wm * 64 + i * 16 + quad * 4 + r;
                out[(size_t)m * CDIM + n] = acc[i][j][r] + bv;
            }
    }
}

// ---------------------------------------------------------------------------
// Flash attention, R11 split-k grid + ASYNC double-buffered staging:
//   K/V staged via global_load_lds with pre-swizzled SOURCE (linear LDS
//   dest; content identical to the old swz() layout, read side unchanged).
//   One VMC0+LGKM0+BAR per step (was: 2 barriers + reg->LDS round trip).
//   Removes the loop-carried kr/vr register state (R9's spill trigger).
//   qb 0-3 unsplit (y=40..43), qb 4-7 2-way (y=32..39), qb 8-15 4-way
//   (y=0..31); grid (32 bh, 44).  merge_attn combines (unchanged).
// ---------------------------------------------------------------------------

__global__ __launch_bounds__(256) void flash_attn32(
    const unsigned short* __restrict__ Qp,   // [BH, T, 64]  (Q pre-scaled 0.125)
    const unsigned short* __restrict__ Kp,   // [BH, T, 64]
    const unsigned short* __restrict__ Vtp,  // [BH, 64, T]
    const int* __restrict__ mask,            // [B, T]
    unsigned short* __restrict__ Y,          // [B*T, 1024] bf16
    unsigned short* __restrict__ Po,         // [32*40, 128, 64] bf16 partial O
    float* __restrict__ Pm,                  // [32*40, 128] partial m
    float* __restrict__ Pl)                  // [32*40, 128] partial l
{
    __shared__ unsigned short Ks[2][64 * 64];   // dbuf, swizzled content
    __shared__ unsigned short Vs[2][64 * 64];   // dbuf, swizzled (V^T: rows=d)
    __shared__ float mask_arr[2][64];           // dbuf, permuted to reg order
    __shared__ float als[4][32];                // per-warp alpha / 1/l broadcast
    __shared__ int flagu[2];                    // per buf: 0 = all valid

    const int bh = blockIdx.x;
    const int y = blockIdx.y;
    int qb, j0, jstep;
    bool split;
    if (y < 32)      { qb = 15 - (y >> 2);        j0 = y & 3;        jstep = 4; split = true; }
    else if (y < 40) { qb = 7 - ((y - 32) >> 1);  j0 = (y - 32) & 1; jstep = 2; split = true; }
    else             { qb = 43 - y;               j0 = 0;            jstep = 1; split = false; }
    // partial index: 2-way at local 0..7, 4-way at local 8..39 (seg == j0)
    const int pidx = split
        ? ((qb < 8) ? (bh * 40 + (qb - 4) * 2 + j0)
                    : (bh * 40 + 8 + (qb - 8) * 4 + j0))
        : 0;

    const int b = bh >> 4, h = bh & 15;
    const int tid = threadIdx.x;
    const int w = tid >> 6, lane = tid & 63;
    const int l31 = lane & 31, hi = lane >> 5;
    const size_t base = (size_t)bh * T_SEQ * HD;
    const int qB = qb * 128;
    const int qw0 = qB + w * 32;
    const int qv = qw0 + l31;                // this lane's softmax q-row
    const int jlast = 2 * qb + 1;

    // async staging geometry: wave w covers rows rw0..rw0+7 per call;
    // source chunk pre-swizzled so linear LDS dest == old swz() layout.
    const int rw0 = w * 8;                   // wave-uniform row base
    const int rl = lane >> 3;                // 0..7 per-lane row offset
    const int sc8 = (((lane & 7) ^ rl) & 7) * 8;  // pre-swizzled source chunk (elems)

    // Q fragments: qf[c] = Q[qv][c*16 + hi*8 .. +8]  (B-operand of swapped QK^T)
    U16x8 qf[4];
    {
        const unsigned short* qrow = &Qp[base + (size_t)qv * HD];
#pragma unroll
        for (int c = 0; c < 4; ++c)
            qf[c].u4 = *(const uint4*)&qrow[c * 16 + hi * 8];
    }

    f32x16 oA0, oA1;
#pragma unroll
    for (int r = 0; r < 16; ++r) { oA0[r] = 0.f; oA1[r] = 0.f; }
    float m_r = -3.0e38f, mL = 0.f, l_r = 0.f;

    // ---- stage tile j0 into buffer 0
    {
        const int t = j0;
        async_copy16(&Kp[base + (size_t)(t * 64 + rw0 + rl) * HD + sc8],      &Ks[0][rw0 * 64]);
        async_copy16(&Kp[base + (size_t)(t * 64 + 32 + rw0 + rl) * HD + sc8], &Ks[0][(rw0 + 32) * 64]);
        async_copy16(&Vtp[base + (size_t)(rw0 + rl) * T_SEQ + t * 64 + sc8],      &Vs[0][rw0 * 64]);
        async_copy16(&Vtp[base + (size_t)(32 + rw0 + rl) * T_SEQ + t * 64 + sc8], &Vs[0][(rw0 + 32) * 64]);
        if (w == 0) {
            const float mfv = mask[b * T_SEQ + t * 64 + lane] ? 0.f : -1.0e30f;
            const int k = lane;
            const int idx = ((k >> 2) & 1) * 32 + (k >> 5) * 16 + ((k & 31) >> 3) * 4 + (k & 3);
            mask_arr[0][idx] = mfv;
            const unsigned long long bb = __ballot(mfv == 0.f);
            if (lane == 0) flagu[0] = (bb == 0xFFFFFFFFFFFFFFFFull) ? 0 : 1;
        }
    }
    VMC0(); LGKM0(); BAR();

    int p = 0;
    for (int j = j0; j <= jlast; j += jstep) {
        const int jn = j + jstep;
        if (jn <= jlast) {   // issue next tile's async stage into buf p^1
            const int t = jn, q = p ^ 1;
            async_copy16(&Kp[base + (size_t)(t * 64 + rw0 + rl) * HD + sc8],      &Ks[q][rw0 * 64]);
            async_copy16(&Kp[base + (size_t)(t * 64 + 32 + rw0 + rl) * HD + sc8], &Ks[q][(rw0 + 32) * 64]);
            async_copy16(&Vtp[base + (size_t)(rw0 + rl) * T_SEQ + t * 64 + sc8],      &Vs[q][rw0 * 64]);
            async_copy16(&Vtp[base + (size_t)(32 + rw0 + rl) * T_SEQ + t * 64 + sc8], &Vs[q][(rw0 + 32) * 64]);
            if (w == 0) {
                const float mfv = mask[b * T_SEQ + t * 64 + lane] ? 0.f : -1.0e30f;
                const int k = lane;
                const int idx = ((k >> 2) & 1) * 32 + (k >> 5) * 16 + ((k & 31) >> 3) * 4 + (k & 3);
                mask_arr[q][idx] = mfv;
                const unsigned long long bb = __ballot(mfv == 0.f);
                if (lane == 0) flagu[q] = (bb == 0xFFFFFFFFFFFFFFFFull) ? 0 : 1;
            }
        }

        const bool skipw = (j * 64 > qw0 + 31);
        if (!skipw) {
            const bool edge = (j * 64 + 63 > qw0);
            const int anymask = flagu[p];
            const unsigned short* KsP = Ks[p];
            const unsigned short* VsP = Vs[p];

            // ---- S^T = K Q^T  (two 32-k halves; Q pre-scaled)
            f32x16 sc0, sc1;
#pragma unroll
            for (int r = 0; r < 16; ++r) { sc0[r] = 0.f; sc1[r] = 0.f; }
#pragma unroll
            for (int c = 0; c < 4; ++c) {
                U16x8 ka0, ka1;
                const int r0 = l31, r1 = 32 + l31;
                ka0.u4 = *(const uint4*)&KsP[r0 * 64 + (((2 * c + hi) ^ (r0 & 7)) << 3)];
                ka1.u4 = *(const uint4*)&KsP[r1 * 64 + (((2 * c + hi) ^ (r1 & 7)) << 3)];
                sc0 = __builtin_amdgcn_mfma_f32_32x32x16_bf16(ka0.b, qf[c].b, sc0, 0, 0, 0);
                sc1 = __builtin_amdgcn_mfma_f32_32x32x16_bf16(ka1.b, qf[c].b, sc1, 0, 0, 0);
            }

            // ---- pad mask (pure add; scale already folded into Q)
            if (anymask) {
#pragma unroll
                for (int g = 0; g < 4; ++g) {
                    const f32x4 m0v = *(const f32x4*)&mask_arr[p][hi * 32 + g * 4];
                    const f32x4 m1v = *(const f32x4*)&mask_arr[p][hi * 32 + 16 + g * 4];
#pragma unroll
                    for (int t = 0; t < 4; ++t) {
                        sc0[g * 4 + t] += m0v[t];
                        sc1[g * 4 + t] += m1v[t];
                    }
                }
            }
            // ---- causal edge: k_global > q -> -inf
            if (edge) {
#pragma unroll
                for (int r = 0; r < 16; ++r) {
                    const int krow = (r & 3) + 8 * (r >> 2) + 4 * hi;
                    if (j * 64 + krow > qv)      sc0[r] = -1.0e30f;
                    if (j * 64 + 32 + krow > qv) sc1[r] = -1.0e30f;
                }
            }

            // ---- tile max (in-lane 32 values, then lane<->lane+32 merge)
            float tm = -3.0e38f;
#pragma unroll
            for (int r = 0; r < 16; ++r)
                tm = fmaxf(tm, fmaxf(sc0[r], sc1[r]));
            tm = fmaxf(tm, __shfl_xor(tm, 32));

            // ---- defer-max: rescale only if max grew > THR
            if (__any(tm > m_r + 8.f)) {
                const float mn = fmaxf(m_r, tm);
                const float a = __builtin_amdgcn_exp2f((m_r - mn) * LOG2E);
                m_r = mn; mL = mn * LOG2E;
                l_r *= a;
                if (hi == 0) als[w][l31] = a;      // alpha indexed by q
                f32x4 av[4];
#pragma unroll
                for (int g = 0; g < 4; ++g)
                    av[g] = *(const f32x4*)&als[w][g * 8 + hi * 4];
#pragma unroll
                for (int r = 0; r < 16; ++r) {
                    const float aa = av[r >> 2][r & 3];
                    oA0[r] *= aa; oA1[r] *= aa;
                }
            }

            // ---- exp + per-lane partial sum
            float ps = 0.f;
#pragma unroll
            for (int r = 0; r < 16; ++r) {
                const float p0 = __builtin_amdgcn_exp2f(fmaf(sc0[r], LOG2E, -mL));
                const float p1 = __builtin_amdgcn_exp2f(fmaf(sc1[r], LOG2E, -mL));
                sc0[r] = p0; sc1[r] = p1;
                ps += p0 + p1;
            }
            l_r += ps;

            // ---- P -> bf16 A-frags (cvt_pk + permlane32_swap) ; O += P V
#pragma unroll
            for (int c = 0; c < 4; ++c) {
                const int rb = (c & 1) * 8;
                unsigned int x0, y0, x1, y1;
                if (c < 2) {
                    x0 = cvtpk_bf16(sc0[rb + 0], sc0[rb + 1]);
                    y0 = cvtpk_bf16(sc0[rb + 4], sc0[rb + 5]);
                    x1 = cvtpk_bf16(sc0[rb + 2], sc0[rb + 3]);
                    y1 = cvtpk_bf16(sc0[rb + 6], sc0[rb + 7]);
                } else {
                    x0 = cvtpk_bf16(sc1[rb + 0], sc1[rb + 1]);
                    y0 = cvtpk_bf16(sc1[rb + 4], sc1[rb + 5]);
                    x1 = cvtpk_bf16(sc1[rb + 2], sc1[rb + 3]);
                    y1 = cvtpk_bf16(sc1[rb + 6], sc1[rb + 7]);
                }
                plane32swap(x0, y0);   // x0 -> au[0] (j=0,1), y0 -> au[2] (j=4,5)
                plane32swap(x1, y1);   // x1 -> au[1] (j=2,3), y1 -> au[3] (j=6,7)
                U16x8 pa;
                pa.u4 = make_uint4(x0, x1, y0, y1);
                {
                    const int vr_0 = l31, vr_1 = 32 + l31;
                    U16x8 vb0, vb1;
                    vb0.u4 = *(const uint4*)&VsP[vr_0 * 64 + (((2 * c + hi) ^ (vr_0 & 7)) << 3)];
                    vb1.u4 = *(const uint4*)&VsP[vr_1 * 64 + (((2 * c + hi) ^ (vr_1 & 7)) << 3)];
                    oA0 = __builtin_amdgcn_mfma_f32_32x32x16_bf16(pa.b, vb0.b, oA0, 0, 0, 0);
                    oA1 = __builtin_amdgcn_mfma_f32_32x32x16_bf16(pa.b, vb1.b, oA1, 0, 0, 0);
                }
            }
        }

        VMC0(); LGKM0(); BAR();   // next buffer staged; all waves done with p
        p ^= 1;
    }

    // ---- hi-merge of the row-sum partial (each lane covers its hi-half)
    const float lt = l_r + __shfl_xor(l_r, 32);

    if (split) {
        // ---- write unnormalized partials (O-layout rows, lane-q m/l)
        if (hi == 0) {
            Pm[pidx * 128 + w * 32 + l31] = m_r;
            Pl[pidx * 128 + w * 32 + l31] = lt;
        }
#pragma unroll
        for (int r = 0; r < 16; ++r) {
            const int qlc = w * 32 + (r & 3) + 8 * (r >> 2) + 4 * hi;
            Po[(size_t)pidx * 8192 + qlc * 64 + l31]      = f2bf(oA0[r]);
            Po[(size_t)pidx * 8192 + qlc * 64 + 32 + l31] = f2bf(oA1[r]);
        }
    } else {
        // ---- normalize + store
        if (hi == 0) als[w][l31] = 1.0f / lt;
        f32x4 lv[4];
#pragma unroll
        for (int g = 0; g < 4; ++g)
            lv[g] = *(const f32x4*)&als[w][g * 8 + hi * 4];
#pragma unroll
        for (int r = 0; r < 16; ++r) {
            const int q = qw0 + (r & 3) + 8 * (r >> 2) + 4 * hi;
            const float sl = lv[r >> 2][r & 3];
            const size_t row = (size_t)(b * T_SEQ + q);
            Y[row * CDIM + h * HD + l31]      = f2bf(oA0[r] * sl);
            Y[row * CDIM + h * HD + 32 + l31] = f2bf(oA1[r] * sl);
        }
    }
}

// ---------------------------------------------------------------------------
// Merge the S segments of each split (bh, qb in 4..15) chunk.
//   O = (sum_s f_s*O_s) / (sum_s f_s*l_s),  f_s = exp(m_s - max_s m_s).
//   S = 2 for qb 4..7, S = 4 for qb 8..15.
//   grid 1536 = 32 bh x 12 qb x 4 parts; thread -> (q row, 8 d cols).
// ---------------------------------------------------------------------------
__global__ __launch_bounds__(256) void merge_attn(
    const unsigned short* __restrict__ Po,
    const float* __restrict__ Pm, const float* __restrict__ Pl,
    unsigned short* __restrict__ Y)
{
    const int u = blockIdx.x;
    const int bh = u & 31;
    const int v = u >> 5;                 // 0..47
    const int qb = 4 + (v >> 2), part = v & 3;
    const int tid = threadIdx.x;
    const int ql = part * 32 + (tid >> 3);
    const int d0 = (tid & 7) * 8;
    const int b = bh >> 4, h = bh & 15;

    int S, basei;
    if (qb < 8) { S = 2; basei = bh * 40 + (qb - 4) * 2; }
    else        { S = 4; basei = bh * 40 + 8 + (qb - 8) * 4; }

    float mv[4], lv[4];
    float M = -3.0e38f;
#pragma unroll
    for (int s = 0; s < 4; ++s) {
        if (s < S) {
            mv[s] = Pm[(basei + s) * 128 + ql];
            lv[s] = Pl[(basei + s) * 128 + ql];
            M = fmaxf(M, mv[s]);
        }
    }
    float f[4], L = 0.f;
#pragma unroll
    for (int s = 0; s < 4; ++s) {
        if (s < S) {
            f[s] = __builtin_amdgcn_exp2f((mv[s] - M) * LOG2E);
            L += f[s] * lv[s];
        }
    }
    const float inv = 1.0f / L;

    float o[8] = {0.f, 0.f, 0.f, 0.f, 0.f, 0.f, 0.f, 0.f};
#pragma unroll
    for (int s = 0; s < 4; ++s) {
        if (s < S) {
            U16x8 a;
            a.u4 = *(const uint4*)&Po[(size_t)(basei + s) * 8192 + ql * 64 + d0];
#pragma unroll
            for (int j = 0; j < 8; ++j) o[j] += f[s] * bf2f(a.s[j]);
        }
    }

    U16x8 ot;
#pragma unroll
    for (int j = 0; j < 8; ++j) ot.s[j] = f2bf(o[j] * inv);

    const int q = qb * 128 + ql;
    *(uint4*)&Y[(size_t)(b * T_SEQ + q) * CDIM + h * HD + d0] = ot.u4;
}

// ---------------------------------------------------------------------------
extern "C" void kernel_launch(void* const* d_in, const int* in_sizes, int n_in,
                              void* d_out, int out_size, void* d_ws, size_t ws_size,
                              hipStream_t stream)
{
    const float* X     = (const float*)d_in[0];
    const int*   mask  = (const int*)d_in[1];
    const float* Wqkv  = (const float*)d_in[2];
    const float* bqkv  = (const float*)d_in[3];
    const float* Wproj = (const float*)d_in[4];
    const float* bproj = (const float*)d_in[5];
    float* out = (float*)d_out;

    const size_t per = (size_t)2 * NHEAD * T_SEQ * HD;   // 4,194,304 elems
    unsigned short* Qp     = (unsigned short*)d_ws;
    unsigned short* Kp     = Qp + per;
    unsigned short* Vtp    = Kp + per;
    unsigned short* Xb     = Vtp + per;                  // aliased: Yp reuses Xb
    unsigned short* Yp     = Xb;                         // X consumed before Y written
    unsigned short* Wprojt = Xb + per;                   // [1024,1024]
    unsigned short* Wqkvt  = Wprojt + (size_t)CDIM * CDIM;     // [3072,1024]
    // Po aliases Wqkvt (dead after qkv8; stream-ordered) and extends past it
    unsigned short* Po     = Wqkvt;                      // [1280,128,64] bf16
    float*          Pm     = (float*)(Po + (size_t)1280 * 8192);
    float*          Pl     = Pm + 1280 * 128;

    prep<<<3072, 256, 0, stream>>>(X, Xb, Wqkv, Wqkvt, Wproj, Wprojt);
    qkv8<<<192, 512, 0, stream>>>(Xb, Wqkvt, bqkv, Qp, Kp, Vtp);
    flash_attn32<<<dim3(2 * NHEAD, 44), 256, 0, stream>>>(Qp, Kp, Vtp, mask, Yp, Po, Pm, Pl);
    merge_attn<<<1536, 256, 0, stream>>>(Po, Pm, Pl, Yp);
    proj_gemm<<<dim3(8, 32), 256, 0, stream>>>(Yp, Wprojt, bproj, out);
}